// Round 7
// baseline (408.323 us; speedup 1.0000x reference)
//
#include <hip/hip_runtime.h>
#include <hip/hip_bf16.h>

// SlotAttention fused implementation, round 7 = round-2 code exactly,
// with phaseA launched TWICE (idempotent) as a timing probe:
// dur_us - 240 = true phaseA duration. Diagnostic round.

#define N_TOK 262144
#define CIN 512
#define TILE_M 64
#define NBLK_A 512
#define NBLK_I2 1024
#define PSTRIDE 1024

typedef __attribute__((ext_vector_type(8))) short short8;
typedef __attribute__((ext_vector_type(4))) float f32x4;

__device__ __forceinline__ unsigned short f2bf(float f) {
    union { float f; unsigned u; } v; v.f = f;
    unsigned r = v.u + 0x7FFFu + ((v.u >> 16) & 1u);
    return (unsigned short)(r >> 16);
}
__device__ __forceinline__ unsigned pkbf(float a, float b) {
    return (unsigned)f2bf(a) | ((unsigned)f2bf(b) << 16);
}
__device__ __forceinline__ float bf2f(unsigned short u) {
    union { unsigned u; float f; } v; v.u = ((unsigned)u) << 16;
    return v.f;
}
__device__ __forceinline__ float sigmoidf_(float x) { return 1.f / (1.f + expf(-x)); }

__device__ __forceinline__ float q_from_slot(float v, const float* __restrict__ g,
                                             const float* __restrict__ b,
                                             const float* __restrict__ W, int lane) {
    float s = v, s2 = v * v;
#pragma unroll
    for (int d = 1; d < 64; d <<= 1) { s += __shfl_xor(s, d); s2 += __shfl_xor(s2, d); }
    float mean = s * (1.f / 64.f);
    float var = s2 * (1.f / 64.f) - mean * mean;
    float rstd = rsqrtf(var + 1e-3f);
    float hl = (v - mean) * rstd * g[lane] + b[lane];
    float acc = 0.f;
    for (int i = 0; i < 64; ++i) acc += __shfl(hl, i) * W[i * 64 + lane];
    return acc * 0.125f;
}

// ------- wt_init: blocks 0..127 build Wt (g*W bf16, transposed) + c1/c2; block 128 = slot init -------
__global__ __launch_bounds__(256) void wt_init_kernel(
    const float* __restrict__ Wk, const float* __restrict__ Wv,
    const float* __restrict__ ln_g, const float* __restrict__ ln_b,
    unsigned short* __restrict__ Wt, float* __restrict__ c12,
    const float* __restrict__ noise_fg, const float* __restrict__ noise_bg,
    const float* __restrict__ mu_fg, const float* __restrict__ ls_fg,
    const float* __restrict__ mu_bg, const float* __restrict__ ls_bg,
    const float* __restrict__ qbg_g, const float* __restrict__ qbg_b, const float* __restrict__ qbg_W,
    const float* __restrict__ qfg_g, const float* __restrict__ qfg_b, const float* __restrict__ qfg_W,
    float* __restrict__ slots_ws, float* __restrict__ q_ws) {
    int t = threadIdx.x;
    if (blockIdx.x < 128) {
        int j = blockIdx.x;
        const float* W = (j < 64) ? Wk : Wv;
        int jc = j & 63;
        float c1 = 0.f, c2 = 0.f;
        for (int i = t; i < 512; i += 256) {
            float wv = W[i * 64 + jc];
            float g = ln_g[i], b = ln_b[i];
            c1 += g * wv; c2 += b * wv;
            Wt[(size_t)j * 512 + i] = f2bf(g * wv);
        }
        __shared__ float s1[4], s2[4];
#pragma unroll
        for (int d = 1; d < 64; d <<= 1) { c1 += __shfl_xor(c1, d); c2 += __shfl_xor(c2, d); }
        if ((t & 63) == 0) { s1[t >> 6] = c1; s2[t >> 6] = c2; }
        __syncthreads();
        if (t == 0) {
            c12[j] = (s1[0] + s1[1]) + (s1[2] + s1[3]);
            c12[128 + j] = (s2[0] + s2[1]) + (s2[2] + s2[3]);
        }
    } else {
        if (t < 192) {
            int s = t >> 6, c = t & 63;
            float v = (s == 0) ? (mu_bg[c] + expf(ls_bg[c]) * noise_bg[c])
                               : (mu_fg[c] + expf(ls_fg[c]) * noise_fg[(s - 1) * 64 + c]);
            slots_ws[t] = v;
            const float* g = s ? qfg_g : qbg_g;
            const float* b = s ? qfg_b : qbg_b;
            const float* W = s ? qfg_W : qbg_W;
            q_ws[t] = q_from_slot(v, g, b, W, c);
        }
    }
}

// ------- phase A: stats + raw-x bf16 stage + MFMA + affine fixup + iter1 attn partials -------
__global__ __launch_bounds__(256, 2) void phaseA_kernel(
    const float* __restrict__ x, const unsigned short* __restrict__ Wt,
    const float* __restrict__ c12, const float* __restrict__ qv,
    unsigned short* __restrict__ kb, unsigned short* __restrict__ vb,
    float* __restrict__ partials) {
    __shared__ unsigned short SA[TILE_M * CIN];  // 64KB bf16 (swizzled); aliased as kvf f32 after MFMA
    __shared__ float q_s[192];
    __shared__ float w_s[64 * 4];
    __shared__ float2 rowstat[64];  // (rstd, mean*rstd)
    float* kvf = (float*)SA;        // [64][130]

    const int t = threadIdx.x;
    const int lane = t & 63;
    const int w = t >> 6;

    if (t < 192) q_s[t] = qv[t];

    short8 bfrag[16][2];
    float c1r[2], c2r[2];
#pragma unroll
    for (int nt = 0; nt < 2; ++nt) {
        int col = w * 32 + nt * 16 + (lane & 15);
        c1r[nt] = c12[col];
        c2r[nt] = c12[128 + col];
#pragma unroll
        for (int kk = 0; kk < 16; ++kk) {
            int off = kk * 32 + ((lane >> 4) << 3);
            bfrag[kk][nt] = *(const short8*)(Wt + (size_t)col * 512 + off);
        }
    }

    float upd_acc = 0.f;
    float sw_acc = 0.f;

    for (int tile = blockIdx.x; tile < N_TOK / TILE_M; tile += NBLK_A) {
        const size_t row0 = (size_t)tile * TILE_M;
        __syncthreads();

        // ---- P1: 8 lanes per row -> sums + bf16 stage ----
#pragma unroll
        for (int p = 0; p < 2; ++p) {
            int r = w * 16 + p * 8 + (lane >> 3);
            int c8 = lane & 7;
            const float4* xr = (const float4*)(x + (row0 + r) * CIN) + c8 * 16;
            char* rowbase = (char*)SA + r * 1024;
            int bb = c8 * 128;
            int sw = (r & 7) << 4;
            float s = 0.f, s2 = 0.f;
#pragma unroll
            for (int i = 0; i < 8; ++i) {
                float4 a = xr[2 * i];
                float4 b = xr[2 * i + 1];
                s += (a.x + a.y) + (a.z + a.w) + (b.x + b.y) + (b.z + b.w);
                s2 = fmaf(a.x, a.x, s2); s2 = fmaf(a.y, a.y, s2);
                s2 = fmaf(a.z, a.z, s2); s2 = fmaf(a.w, a.w, s2);
                s2 = fmaf(b.x, b.x, s2); s2 = fmaf(b.y, b.y, s2);
                s2 = fmaf(b.z, b.z, s2); s2 = fmaf(b.w, b.w, s2);
                uint4 o;
                o.x = pkbf(a.x, a.y); o.y = pkbf(a.z, a.w);
                o.z = pkbf(b.x, b.y); o.w = pkbf(b.z, b.w);
                *(uint4*)(rowbase + ((bb + i * 16) ^ sw)) = o;
            }
#pragma unroll
            for (int d = 1; d < 8; d <<= 1) { s += __shfl_xor(s, d); s2 += __shfl_xor(s2, d); }
            if (c8 == 0) {
                float mean = s * (1.f / 512.f);
                float var = s2 * (1.f / 512.f) - mean * mean;
                float rstd = rsqrtf(var + 1e-3f);
                rowstat[r] = make_float2(rstd, mean * rstd);
            }
        }
        __syncthreads();

        // ---- P2: MFMA ----
        f32x4 acc[4][2];
#pragma unroll
        for (int m = 0; m < 4; ++m) {
            acc[m][0] = (f32x4){0.f, 0.f, 0.f, 0.f};
            acc[m][1] = (f32x4){0.f, 0.f, 0.f, 0.f};
        }
#pragma unroll
        for (int kk = 0; kk < 16; ++kk) {
#pragma unroll
            for (int m = 0; m < 4; ++m) {
                int row = m * 16 + (lane & 15);
                int boff = (kk * 64 + ((lane >> 4) << 4)) ^ ((row & 7) << 4);
                short8 af = *(const short8*)((const char*)SA + row * 1024 + boff);
                acc[m][0] = __builtin_amdgcn_mfma_f32_16x16x32_bf16(af, bfrag[kk][0], acc[m][0], 0, 0, 0);
                acc[m][1] = __builtin_amdgcn_mfma_f32_16x16x32_bf16(af, bfrag[kk][1], acc[m][1], 0, 0, 0);
            }
        }
        __syncthreads();

        // ---- P3: affine fixup + write kvf ----
        float2 rs[16];
#pragma unroll
        for (int m = 0; m < 4; ++m)
#pragma unroll
            for (int j = 0; j < 4; ++j)
                rs[m * 4 + j] = rowstat[m * 16 + ((lane >> 4) << 2) + j];
#pragma unroll
        for (int m = 0; m < 4; ++m)
#pragma unroll
            for (int n = 0; n < 2; ++n)
#pragma unroll
                for (int j = 0; j < 4; ++j) {
                    int row = m * 16 + ((lane >> 4) << 2) + j;
                    int col = w * 32 + n * 16 + (lane & 15);
                    float val = fmaf(rs[m * 4 + j].x, acc[m][n][j],
                                     fmaf(-rs[m * 4 + j].y, c1r[n], c2r[n]));
                    kvf[row * 130 + col] = val;
                }
        __syncthreads();

        // ---- P4: bf16 store of k,v + wave0 softmax weights ----
        {
            int r = t >> 2, q4 = t & 3;
            unsigned short* dst = ((q4 < 2) ? kb : vb) + (row0 + r) * 64 + (q4 & 1) * 32;
            const float* src = &kvf[r * 130 + q4 * 32];
#pragma unroll
            for (int j = 0; j < 32; j += 8) {
                float2 p0 = *(const float2*)(src + j);
                float2 p1 = *(const float2*)(src + j + 2);
                float2 p2 = *(const float2*)(src + j + 4);
                float2 p3 = *(const float2*)(src + j + 6);
                uint4 o;
                o.x = pkbf(p0.x, p0.y);
                o.y = pkbf(p1.x, p1.y);
                o.z = pkbf(p2.x, p2.y);
                o.w = pkbf(p3.x, p3.y);
                *(uint4*)(dst + j) = o;
            }
        }
        if (t < 64) {
            int r = t;
            float l0 = 0.f, l1 = 0.f, l2 = 0.f;
#pragma unroll 8
            for (int c = 0; c < 64; c += 2) {
                float2 kv2 = *(const float2*)&kvf[r * 130 + c];
                l0 += kv2.x * q_s[c] + kv2.y * q_s[c + 1];
                l1 += kv2.x * q_s[64 + c] + kv2.y * q_s[64 + c + 1];
                l2 += kv2.x * q_s[128 + c] + kv2.y * q_s[128 + c + 1];
            }
            float mx = fmaxf(l0, fmaxf(l1, l2));
            float e0 = expf(l0 - mx), e1 = expf(l1 - mx), e2 = expf(l2 - mx);
            float inv = 1.f / (e0 + e1 + e2);
            w_s[r * 4 + 0] = e0 * inv + 1e-8f;
            w_s[r * 4 + 1] = e1 * inv + 1e-8f;
            w_s[r * 4 + 2] = e2 * inv + 1e-8f;
        }
        __syncthreads();

        // ---- P5: outer-product partial accumulate ----
        if (t < 192) {
            int s = t >> 6, c = t & 63;
            float a = 0.f;
            for (int r = 0; r < 64; ++r) a += w_s[r * 4 + s] * kvf[r * 130 + 64 + c];
            upd_acc += a;
        } else if (t < 195) {
            int s = t - 192;
            float a = 0.f;
            for (int r = 0; r < 64; ++r) a += w_s[r * 4 + s];
            sw_acc += a;
        }
    }
    if (t < 192) partials[(size_t)t * PSTRIDE + blockIdx.x] = upd_acc;
    else if (t < 195) partials[(size_t)t * PSTRIDE + blockIdx.x] = sw_acc;
}

// ------- iter 2: attention with q2, writes attn.T + partials (transposed) -------
__global__ __launch_bounds__(256) void iter2_kernel(
    const unsigned short* __restrict__ kb, const unsigned short* __restrict__ vb,
    const float* __restrict__ qv, float* __restrict__ attn_out, float* __restrict__ partials) {
    __shared__ float q_s[192];
    __shared__ float w_s[256 * 4];
    __shared__ unsigned short v_lds[256 * 64];
    int t = threadIdx.x;
    if (t < 192) q_s[t] = qv[t];
    __syncthreads();
    size_t r = (size_t)blockIdx.x * 256 + t;
    const unsigned short* krow = kb + r * 64;
    float l0 = 0.f, l1 = 0.f, l2 = 0.f;
#pragma unroll
    for (int i = 0; i < 8; ++i) {
        uint4 u = *(const uint4*)(krow + i * 8);
        unsigned uu[4] = {u.x, u.y, u.z, u.w};
#pragma unroll
        for (int p = 0; p < 4; ++p) {
            float fa = bf2f((unsigned short)(uu[p] & 0xffffu));
            float fb = bf2f((unsigned short)(uu[p] >> 16));
            int c = i * 8 + p * 2;
            l0 += fa * q_s[c] + fb * q_s[c + 1];
            l1 += fa * q_s[64 + c] + fb * q_s[64 + c + 1];
            l2 += fa * q_s[128 + c] + fb * q_s[128 + c + 1];
        }
    }
    float mx = fmaxf(l0, fmaxf(l1, l2));
    float e0 = expf(l0 - mx), e1 = expf(l1 - mx), e2 = expf(l2 - mx);
    float inv = 1.f / (e0 + e1 + e2);
    float a0 = e0 * inv, a1 = e1 * inv, a2 = e2 * inv;
    attn_out[r] = a0;
    attn_out[(size_t)N_TOK + r] = a1;
    attn_out[2 * (size_t)N_TOK + r] = a2;
    w_s[t * 4 + 0] = a0 + 1e-8f;
    w_s[t * 4 + 1] = a1 + 1e-8f;
    w_s[t * 4 + 2] = a2 + 1e-8f;
    {
        const uint4* vr = (const uint4*)(vb + r * 64);
        uint4* vl = (uint4*)(v_lds + t * 64);
#pragma unroll
        for (int i = 0; i < 8; ++i) vl[i] = vr[i];
    }
    __syncthreads();
    if (t < 192) {
        int s = t >> 6, c = t & 63;
        float part = 0.f;
        for (int r2 = 0; r2 < 256; ++r2) part += w_s[r2 * 4 + s] * bf2f(v_lds[r2 * 64 + c]);
        partials[(size_t)t * PSTRIDE + blockIdx.x] = part;
    } else if (t < 195) {
        int s = t - 192;
        float part = 0.f;
        for (int r2 = 0; r2 < 256; ++r2) part += w_s[r2 * 4 + s];
        partials[(size_t)t * PSTRIDE + blockIdx.x] = part;
    }
}

// ------- reduce: 195 blocks, one per column -------
__global__ __launch_bounds__(256) void reduce_kernel(const float* __restrict__ partials,
                                                     int nblk, float* __restrict__ reduced) {
    int col = blockIdx.x, t = threadIdx.x;
    float a = 0.f;
    for (int b = t; b < nblk; b += 256) a += partials[(size_t)col * PSTRIDE + b];
#pragma unroll
    for (int d = 1; d < 64; d <<= 1) a += __shfl_xor(a, d);
    __shared__ float ws_[4];
    if ((t & 63) == 0) ws_[t >> 6] = a;
    __syncthreads();
    if (t == 0) reduced[col] = (ws_[0] + ws_[1]) + (ws_[2] + ws_[3]);
}

// ------- update: GRU -> MLP -> (q | out slots) -------
__global__ __launch_bounds__(256) void update_kernel(
    const float* __restrict__ reduced,
    float* __restrict__ slots_ws, float* __restrict__ q_ws,
    const float* __restrict__ gbg_k, const float* __restrict__ gbg_rk, const float* __restrict__ gbg_bias,
    const float* __restrict__ gfg_k, const float* __restrict__ gfg_rk, const float* __restrict__ gfg_bias,
    const float* __restrict__ mbg_g, const float* __restrict__ mbg_b, const float* __restrict__ mbg_W1,
    const float* __restrict__ mbg_b1, const float* __restrict__ mbg_W2, const float* __restrict__ mbg_b2,
    const float* __restrict__ mfg_g, const float* __restrict__ mfg_b, const float* __restrict__ mfg_W1,
    const float* __restrict__ mfg_b1, const float* __restrict__ mfg_W2, const float* __restrict__ mfg_b2,
    const float* __restrict__ qbg_g, const float* __restrict__ qbg_b, const float* __restrict__ qbg_W,
    const float* __restrict__ qfg_g, const float* __restrict__ qfg_b, const float* __restrict__ qfg_W,
    int compute_q, float* __restrict__ out_slots) {
    __shared__ float upd[192], hslots[192], swv[3];
    __shared__ float xm[192], hm[192], gout[64], lnv[64], hid[64];
    int t = threadIdx.x;
    if (t < 192) { hslots[t] = slots_ws[t]; upd[t] = reduced[t]; }
    else if (t < 195) swv[t - 192] = reduced[t];
    __syncthreads();
    if (t < 192) upd[t] = upd[t] / swv[t >> 6];
    __syncthreads();

    for (int s = 0; s < 3; ++s) {
        const float* K = s ? gfg_k : gbg_k;
        const float* RK = s ? gfg_rk : gbg_rk;
        const float* BS = s ? gfg_bias : gbg_bias;
        if (t < 192) {
            float ax = BS[t], ah = BS[192 + t];
            const float* us = upd + s * 64;
            const float* hs = hslots + s * 64;
            for (int i = 0; i < 64; ++i) {
                ax += us[i] * K[i * 192 + t];
                ah += hs[i] * RK[i * 192 + t];
            }
            xm[t] = ax; hm[t] = ah;
        }
        __syncthreads();
        if (t < 64) {
            float z = sigmoidf_(xm[t] + hm[t]);
            float rg = sigmoidf_(xm[64 + t] + hm[64 + t]);
            float cand = tanhf(xm[128 + t] + rg * hm[128 + t]);
            gout[t] = z * hslots[s * 64 + t] + (1.f - z) * cand;
        }
        __syncthreads();
        const float* MG = s ? mfg_g : mbg_g;
        const float* MB = s ? mfg_b : mbg_b;
        const float* MW1 = s ? mfg_W1 : mbg_W1;
        const float* MB1 = s ? mfg_b1 : mbg_b1;
        const float* MW2 = s ? mfg_W2 : mbg_W2;
        const float* MB2 = s ? mfg_b2 : mbg_b2;
        if (t < 64) {
            float v = gout[t];
            float su = v, sq = v * v;
#pragma unroll
            for (int d = 1; d < 64; d <<= 1) { su += __shfl_xor(su, d); sq += __shfl_xor(sq, d); }
            float mean = su * (1.f / 64.f), var = sq * (1.f / 64.f) - mean * mean;
            float rstd = rsqrtf(var + 1e-3f);
            lnv[t] = (v - mean) * rstd * MG[t] + MB[t];
        }
        __syncthreads();
        if (t < 64) {
            float a = MB1[t];
            for (int i = 0; i < 64; ++i) a += lnv[i] * MW1[i * 64 + t];
            hid[t] = fmaxf(a, 0.f);
        }
        __syncthreads();
        if (t < 64) {
            float a = MB2[t];
            for (int i = 0; i < 64; ++i) a += hid[i] * MW2[i * 64 + t];
            hslots[s * 64 + t] = gout[t] + a;
        }
        __syncthreads();
    }
    if (t < 192) {
        slots_ws[t] = hslots[t];
        if (out_slots) out_slots[t] = hslots[t];
        if (compute_q) {
            int s = t >> 6, lane = t & 63;
            const float* g = s ? qfg_g : qbg_g;
            const float* b = s ? qfg_b : qbg_b;
            const float* W = s ? qfg_W : qbg_W;
            q_ws[t] = q_from_slot(hslots[t], g, b, W, lane);
        }
    }
}

extern "C" void kernel_launch(void* const* d_in, const int* in_sizes, int n_in,
                              void* d_out, int out_size, void* d_ws, size_t ws_size,
                              hipStream_t stream) {
    const float* x        = (const float*)d_in[0];
    const float* noise_fg = (const float*)d_in[1];
    const float* noise_bg = (const float*)d_in[2];
    const float* ln_g     = (const float*)d_in[3];
    const float* ln_b     = (const float*)d_in[4];
    const float* mu_fg    = (const float*)d_in[5];
    const float* ls_fg    = (const float*)d_in[6];
    const float* mu_bg    = (const float*)d_in[7];
    const float* ls_bg    = (const float*)d_in[8];
    const float* Wk       = (const float*)d_in[9];
    const float* Wv       = (const float*)d_in[10];
    const float* qfg_g    = (const float*)d_in[11];
    const float* qfg_b    = (const float*)d_in[12];
    const float* qfg_W    = (const float*)d_in[13];
    const float* qbg_g    = (const float*)d_in[14];
    const float* qbg_b    = (const float*)d_in[15];
    const float* qbg_W    = (const float*)d_in[16];
    const float* gfg_k    = (const float*)d_in[17];
    const float* gfg_rk   = (const float*)d_in[18];
    const float* gfg_bias = (const float*)d_in[19];
    const float* gbg_k    = (const float*)d_in[20];
    const float* gbg_rk   = (const float*)d_in[21];
    const float* gbg_bias = (const float*)d_in[22];
    const float* mfg_g    = (const float*)d_in[23];
    const float* mfg_b    = (const float*)d_in[24];
    const float* mfg_W1   = (const float*)d_in[25];
    const float* mfg_b1   = (const float*)d_in[26];
    const float* mfg_W2   = (const float*)d_in[27];
    const float* mfg_b2   = (const float*)d_in[28];
    const float* mbg_g    = (const float*)d_in[29];
    const float* mbg_b    = (const float*)d_in[30];
    const float* mbg_W1   = (const float*)d_in[31];
    const float* mbg_b1   = (const float*)d_in[32];
    const float* mbg_W2   = (const float*)d_in[33];
    const float* mbg_b2   = (const float*)d_in[34];

    char* ws = (char*)d_ws;
    unsigned short* Wt = (unsigned short*)ws;                  // 131072 B
    float* c12 = (float*)(ws + 131072);                        // 1024 B
    unsigned short* kb = (unsigned short*)(ws + 132096);       // 32 MB
    unsigned short* vb = kb + (size_t)N_TOK * 64;              // 32 MB
    char* ws2 = ws + 132096 + (size_t)2 * N_TOK * 64 * 2;
    float* slots_ws = (float*)ws2;                             // 192
    float* q_ws = slots_ws + 192;                              // 192
    float* reduced = q_ws + 192;                               // 256 (padded)
    float* partials = reduced + 256;                           // 195 * PSTRIDE

    float* out = (float*)d_out;

    wt_init_kernel<<<dim3(129), dim3(256), 0, stream>>>(
        Wk, Wv, ln_g, ln_b, Wt, c12,
        noise_fg, noise_bg, mu_fg, ls_fg, mu_bg, ls_bg,
        qbg_g, qbg_b, qbg_W, qfg_g, qfg_b, qfg_W, slots_ws, q_ws);
    // TIMING PROBE: phaseA twice (idempotent). dur_us - ~240 = phaseA duration.
    phaseA_kernel<<<dim3(NBLK_A), dim3(256), 0, stream>>>(x, Wt, c12, q_ws, kb, vb, partials);
    phaseA_kernel<<<dim3(NBLK_A), dim3(256), 0, stream>>>(x, Wt, c12, q_ws, kb, vb, partials);
    reduce_kernel<<<dim3(195), dim3(256), 0, stream>>>(partials, NBLK_A, reduced);
    update_kernel<<<dim3(1), dim3(256), 0, stream>>>(reduced, slots_ws, q_ws,
        gbg_k, gbg_rk, gbg_bias, gfg_k, gfg_rk, gfg_bias,
        mbg_g, mbg_b, mbg_W1, mbg_b1, mbg_W2, mbg_b2,
        mfg_g, mfg_b, mfg_W1, mfg_b1, mfg_W2, mfg_b2,
        qbg_g, qbg_b, qbg_W, qfg_g, qfg_b, qfg_W, 1, (float*)nullptr);
    iter2_kernel<<<dim3(NBLK_I2), dim3(256), 0, stream>>>(kb, vb, q_ws, out + 192, partials);
    reduce_kernel<<<dim3(195), dim3(256), 0, stream>>>(partials, NBLK_I2, reduced);
    update_kernel<<<dim3(1), dim3(256), 0, stream>>>(reduced, slots_ws, q_ws,
        gbg_k, gbg_rk, gbg_bias, gfg_k, gfg_rk, gfg_bias,
        mbg_g, mbg_b, mbg_W1, mbg_b1, mbg_W2, mbg_b2,
        mfg_g, mfg_b, mfg_W1, mfg_b1, mfg_W2, mfg_b2,
        qbg_g, qbg_b, qbg_W, qfg_g, qfg_b, qfg_W, 0, out);
}

// Round 8
// 279.383 us; speedup vs baseline: 1.4615x; 1.4615x over previous
//
#include <hip/hip_runtime.h>
#include <hip/hip_bf16.h>

// SlotAttention fused implementation, round 8.
// phaseA: producer/consumer wave specialization. 256 blocks x 512 threads, 1/CU.
// Waves 0-3 stream tile t+1 from HBM (stats+bf16 pack -> BUF[cur^1]) while
// waves 4-7 consume BUF[cur] (MFMA -> fixup -> kvf -> k/v store -> wave-local
// softmax + outer product). 3 raw barriers/tile. Rest = round-2 versions.

#define N_TOK 262144
#define CIN 512
#define TILE_M 64
#define NT (N_TOK / TILE_M)
#define NBLK_A 256
#define NBLK_I2 1024
#define PSTRIDE 1024

typedef __attribute__((ext_vector_type(8))) short short8;
typedef __attribute__((ext_vector_type(4))) float f32x4;

__device__ __forceinline__ unsigned short f2bf(float f) {
    union { float f; unsigned u; } v; v.f = f;
    unsigned r = v.u + 0x7FFFu + ((v.u >> 16) & 1u);
    return (unsigned short)(r >> 16);
}
__device__ __forceinline__ unsigned pkbf(float a, float b) {
    return (unsigned)f2bf(a) | ((unsigned)f2bf(b) << 16);
}
__device__ __forceinline__ float bf2f(unsigned short u) {
    union { unsigned u; float f; } v; v.u = ((unsigned)u) << 16;
    return v.f;
}
__device__ __forceinline__ float sigmoidf_(float x) { return 1.f / (1.f + expf(-x)); }

__device__ __forceinline__ float q_from_slot(float v, const float* __restrict__ g,
                                             const float* __restrict__ b,
                                             const float* __restrict__ W, int lane) {
    float s = v, s2 = v * v;
#pragma unroll
    for (int d = 1; d < 64; d <<= 1) { s += __shfl_xor(s, d); s2 += __shfl_xor(s2, d); }
    float mean = s * (1.f / 64.f);
    float var = s2 * (1.f / 64.f) - mean * mean;
    float rstd = rsqrtf(var + 1e-3f);
    float hl = (v - mean) * rstd * g[lane] + b[lane];
    float acc = 0.f;
    for (int i = 0; i < 64; ++i) acc += __shfl(hl, i) * W[i * 64 + lane];
    return acc * 0.125f;
}

// ------- wt_init: blocks 0..127 build Wt (g*W bf16, transposed) + c1/c2; block 128 = slot init -------
__global__ __launch_bounds__(256) void wt_init_kernel(
    const float* __restrict__ Wk, const float* __restrict__ Wv,
    const float* __restrict__ ln_g, const float* __restrict__ ln_b,
    unsigned short* __restrict__ Wt, float* __restrict__ c12,
    const float* __restrict__ noise_fg, const float* __restrict__ noise_bg,
    const float* __restrict__ mu_fg, const float* __restrict__ ls_fg,
    const float* __restrict__ mu_bg, const float* __restrict__ ls_bg,
    const float* __restrict__ qbg_g, const float* __restrict__ qbg_b, const float* __restrict__ qbg_W,
    const float* __restrict__ qfg_g, const float* __restrict__ qfg_b, const float* __restrict__ qfg_W,
    float* __restrict__ slots_ws, float* __restrict__ q_ws) {
    int t = threadIdx.x;
    if (blockIdx.x < 128) {
        int j = blockIdx.x;
        const float* W = (j < 64) ? Wk : Wv;
        int jc = j & 63;
        float c1 = 0.f, c2 = 0.f;
        for (int i = t; i < 512; i += 256) {
            float wv = W[i * 64 + jc];
            float g = ln_g[i], b = ln_b[i];
            c1 += g * wv; c2 += b * wv;
            Wt[(size_t)j * 512 + i] = f2bf(g * wv);
        }
        __shared__ float s1[4], s2[4];
#pragma unroll
        for (int d = 1; d < 64; d <<= 1) { c1 += __shfl_xor(c1, d); c2 += __shfl_xor(c2, d); }
        if ((t & 63) == 0) { s1[t >> 6] = c1; s2[t >> 6] = c2; }
        __syncthreads();
        if (t == 0) {
            c12[j] = (s1[0] + s1[1]) + (s1[2] + s1[3]);
            c12[128 + j] = (s2[0] + s2[1]) + (s2[2] + s2[3]);
        }
    } else {
        if (t < 192) {
            int s = t >> 6, c = t & 63;
            float v = (s == 0) ? (mu_bg[c] + expf(ls_bg[c]) * noise_bg[c])
                               : (mu_fg[c] + expf(ls_fg[c]) * noise_fg[(s - 1) * 64 + c]);
            slots_ws[t] = v;
            const float* g = s ? qfg_g : qbg_g;
            const float* b = s ? qfg_b : qbg_b;
            const float* W = s ? qfg_W : qbg_W;
            q_ws[t] = q_from_slot(v, g, b, W, c);
        }
    }
}

// ------- phase A: producer/consumer wave specialization -------
__global__ __launch_bounds__(512, 1) void phaseA_kernel(
    const float* __restrict__ x, const unsigned short* __restrict__ Wt,
    const float* __restrict__ c12, const float* __restrict__ qv,
    unsigned short* __restrict__ kb, unsigned short* __restrict__ vb,
    float* __restrict__ partials) {
    __shared__ unsigned short BUF[2][TILE_M * CIN];  // 2 x 64KB bf16 (swizzled)
    __shared__ float q_s[192];
    __shared__ float2 rowstat[2][TILE_M];            // (rstd, mean*rstd)

    const int t = threadIdx.x;
    const int lane = t & 63;
    const int w = t >> 6;            // 0..7
    const bool is_prod = (w < 4);
    const int vw = w & 3;            // producer-wave / consumer-wave id 0..3

    if (t < 192) q_s[t] = qv[t];

    // consumer constants (wave-uniform branch; dead for producers)
    short8 bfrag[16][2];
    float c1r[2], c2r[2];
    float u0 = 0.f, u1 = 0.f, u2 = 0.f, sw0 = 0.f, sw1 = 0.f, sw2 = 0.f;
    if (!is_prod) {
#pragma unroll
        for (int nt = 0; nt < 2; ++nt) {
            int col = vw * 32 + nt * 16 + (lane & 15);
            c1r[nt] = c12[col];
            c2r[nt] = c12[128 + col];
#pragma unroll
            for (int kk = 0; kk < 16; ++kk)
                bfrag[kk][nt] = *(const short8*)(Wt + (size_t)col * 512 + kk * 32 + ((lane >> 4) << 3));
        }
    }

    // producer: load rows [vw*16, vw*16+16) of `tile`, stats + swizzled bf16 pack into BUF[b]
    auto produce = [&](int tile, int b) {
#pragma unroll
        for (int p = 0; p < 2; ++p) {
            int r = vw * 16 + p * 8 + (lane >> 3);
            int c8 = lane & 7;
            const float4* xr = (const float4*)(x + ((size_t)tile * TILE_M + r) * CIN) + c8 * 16;
            char* rowbase = (char*)&BUF[b][0] + r * 1024;
            int bb = c8 * 128;
            int sw = (r & 7) << 4;
            float s = 0.f, s2 = 0.f;
#pragma unroll
            for (int i = 0; i < 8; ++i) {
                float4 a = xr[2 * i];
                float4 bq = xr[2 * i + 1];
                s += (a.x + a.y) + (a.z + a.w) + (bq.x + bq.y) + (bq.z + bq.w);
                s2 = fmaf(a.x, a.x, s2); s2 = fmaf(a.y, a.y, s2);
                s2 = fmaf(a.z, a.z, s2); s2 = fmaf(a.w, a.w, s2);
                s2 = fmaf(bq.x, bq.x, s2); s2 = fmaf(bq.y, bq.y, s2);
                s2 = fmaf(bq.z, bq.z, s2); s2 = fmaf(bq.w, bq.w, s2);
                uint4 o;
                o.x = pkbf(a.x, a.y); o.y = pkbf(a.z, a.w);
                o.z = pkbf(bq.x, bq.y); o.w = pkbf(bq.z, bq.w);
                *(uint4*)(rowbase + ((bb + i * 16) ^ sw)) = o;
            }
#pragma unroll
            for (int d = 1; d < 8; d <<= 1) { s += __shfl_xor(s, d); s2 += __shfl_xor(s2, d); }
            if (c8 == 0) {
                float mean = s * (1.f / 512.f);
                float var = s2 * (1.f / 512.f) - mean * mean;
                float rstd = rsqrtf(var + 1e-3f);
                rowstat[b][r] = make_float2(rstd, mean * rstd);
            }
        }
    };

    // prologue: fill BUF[0] with first tile
    if (is_prod) produce(blockIdx.x, 0);
    asm volatile("s_waitcnt vmcnt(0) lgkmcnt(0)" ::: "memory");
    __builtin_amdgcn_s_barrier();

    int cur = 0;
    for (int tile = blockIdx.x; tile < NT; tile += NBLK_A) {
        const size_t row0 = (size_t)tile * TILE_M;
        const int nxt = tile + NBLK_A;
        float* kvf = (float*)&BUF[cur][0];  // [64][130] after M

        f32x4 acc[4][2];
        if (is_prod) {
            if (nxt < NT) produce(nxt, cur ^ 1);
        } else {
            // MFMA from BUF[cur]
#pragma unroll
            for (int m = 0; m < 4; ++m) {
                acc[m][0] = (f32x4){0.f, 0.f, 0.f, 0.f};
                acc[m][1] = (f32x4){0.f, 0.f, 0.f, 0.f};
            }
#pragma unroll
            for (int kk = 0; kk < 16; ++kk) {
#pragma unroll
                for (int m = 0; m < 4; ++m) {
                    int row = m * 16 + (lane & 15);
                    int boff = (kk * 64 + ((lane >> 4) << 4)) ^ ((row & 7) << 4);
                    short8 af = *(const short8*)((const char*)&BUF[cur][0] + row * 1024 + boff);
                    acc[m][0] = __builtin_amdgcn_mfma_f32_16x16x32_bf16(af, bfrag[kk][0], acc[m][0], 0, 0, 0);
                    acc[m][1] = __builtin_amdgcn_mfma_f32_16x16x32_bf16(af, bfrag[kk][1], acc[m][1], 0, 0, 0);
                }
            }
            // affine fixup in place (rowstat[cur] written last iter, stable)
#pragma unroll
            for (int m = 0; m < 4; ++m)
#pragma unroll
                for (int j = 0; j < 4; ++j) {
                    float2 rs = rowstat[cur][m * 16 + ((lane >> 4) << 2) + j];
#pragma unroll
                    for (int n = 0; n < 2; ++n)
                        acc[m][n][j] = fmaf(rs.x, acc[m][n][j], fmaf(-rs.y, c1r[n], c2r[n]));
                }
        }
        asm volatile("s_waitcnt lgkmcnt(0)" ::: "memory");
        __builtin_amdgcn_s_barrier();  // M: consumer reads of BUF[cur] done -> kvf may overwrite

        if (!is_prod) {
#pragma unroll
            for (int m = 0; m < 4; ++m)
#pragma unroll
                for (int n = 0; n < 2; ++n)
#pragma unroll
                    for (int j = 0; j < 4; ++j) {
                        int row = m * 16 + ((lane >> 4) << 2) + j;
                        int col = vw * 32 + n * 16 + (lane & 15);
                        kvf[row * 130 + col] = acc[m][n][j];
                    }
        }
        asm volatile("s_waitcnt lgkmcnt(0)" ::: "memory");
        __builtin_amdgcn_s_barrier();  // B: kvf complete

        if (!is_prod) {
            // P4: bf16 k/v store (consumer-local thread ct covers all 64 rows)
            {
                int ct = t - 256;
                int r = ct >> 2, q4 = ct & 3;
                unsigned short* dst = ((q4 < 2) ? kb : vb) + (row0 + r) * 64 + (q4 & 1) * 32;
                const float* src = &kvf[r * 130 + q4 * 32];
#pragma unroll
                for (int j = 0; j < 32; j += 8) {
                    float2 p0 = *(const float2*)(src + j);
                    float2 p1 = *(const float2*)(src + j + 2);
                    float2 p2 = *(const float2*)(src + j + 4);
                    float2 p3 = *(const float2*)(src + j + 6);
                    uint4 o;
                    o.x = pkbf(p0.x, p0.y);
                    o.y = pkbf(p1.x, p1.y);
                    o.z = pkbf(p2.x, p2.y);
                    o.w = pkbf(p3.x, p3.y);
                    *(uint4*)(dst + j) = o;
                }
            }
            // P5: wave-local softmax + outer product, rows [vw*16, vw*16+16)
            {
                int rr0 = vw * 16;
                int cbase = (lane & 3) * 16;
                float l0 = 0.f, l1 = 0.f, l2 = 0.f;
                const float* kr = &kvf[(rr0 + (lane >> 2)) * 130 + cbase];
#pragma unroll
                for (int i = 0; i < 8; ++i) {
                    float2 kv2 = *(const float2*)(kr + 2 * i);
                    l0 += kv2.x * q_s[cbase + 2 * i] + kv2.y * q_s[cbase + 2 * i + 1];
                    l1 += kv2.x * q_s[64 + cbase + 2 * i] + kv2.y * q_s[64 + cbase + 2 * i + 1];
                    l2 += kv2.x * q_s[128 + cbase + 2 * i] + kv2.y * q_s[128 + cbase + 2 * i + 1];
                }
#pragma unroll
                for (int d = 1; d < 4; d <<= 1) {
                    l0 += __shfl_xor(l0, d); l1 += __shfl_xor(l1, d); l2 += __shfl_xor(l2, d);
                }
                float mx = fmaxf(l0, fmaxf(l1, l2));
                float e0 = expf(l0 - mx), e1 = expf(l1 - mx), e2 = expf(l2 - mx);
                float inv = 1.f / (e0 + e1 + e2);
                float w0v = e0 * inv + 1e-8f;
                float w1v = e1 * inv + 1e-8f;
                float w2v = e2 * inv + 1e-8f;
#pragma unroll
                for (int rr = 0; rr < 16; ++rr) {
                    float b0 = __shfl(w0v, rr * 4);
                    float b1 = __shfl(w1v, rr * 4);
                    float b2 = __shfl(w2v, rr * 4);
                    float vv = kvf[(rr0 + rr) * 130 + 64 + lane];
                    u0 = fmaf(b0, vv, u0); u1 = fmaf(b1, vv, u1); u2 = fmaf(b2, vv, u2);
                    sw0 += b0; sw1 += b1; sw2 += b2;
                }
            }
        }
        asm volatile("s_waitcnt lgkmcnt(0)" ::: "memory");
        __builtin_amdgcn_s_barrier();  // A: kvf reads done; producer LDS writes drained
        cur ^= 1;
    }

    if (!is_prod) {
        int slot = blockIdx.x * 4 + vw;  // 1024 slots total
        partials[(size_t)lane * PSTRIDE + slot] = u0;
        partials[(size_t)(64 + lane) * PSTRIDE + slot] = u1;
        partials[(size_t)(128 + lane) * PSTRIDE + slot] = u2;
        if (lane == 0) {
            partials[(size_t)192 * PSTRIDE + slot] = sw0;
            partials[(size_t)193 * PSTRIDE + slot] = sw1;
            partials[(size_t)194 * PSTRIDE + slot] = sw2;
        }
    }
}

// ------- iter 2: attention with q2, writes attn.T + partials (transposed) -------
__global__ __launch_bounds__(256) void iter2_kernel(
    const unsigned short* __restrict__ kb, const unsigned short* __restrict__ vb,
    const float* __restrict__ qv, float* __restrict__ attn_out, float* __restrict__ partials) {
    __shared__ float q_s[192];
    __shared__ float w_s[256 * 4];
    __shared__ unsigned short v_lds[256 * 64];
    int t = threadIdx.x;
    if (t < 192) q_s[t] = qv[t];
    __syncthreads();
    size_t r = (size_t)blockIdx.x * 256 + t;
    const unsigned short* krow = kb + r * 64;
    float l0 = 0.f, l1 = 0.f, l2 = 0.f;
#pragma unroll
    for (int i = 0; i < 8; ++i) {
        uint4 u = *(const uint4*)(krow + i * 8);
        unsigned uu[4] = {u.x, u.y, u.z, u.w};
#pragma unroll
        for (int p = 0; p < 4; ++p) {
            float fa = bf2f((unsigned short)(uu[p] & 0xffffu));
            float fb = bf2f((unsigned short)(uu[p] >> 16));
            int c = i * 8 + p * 2;
            l0 += fa * q_s[c] + fb * q_s[c + 1];
            l1 += fa * q_s[64 + c] + fb * q_s[64 + c + 1];
            l2 += fa * q_s[128 + c] + fb * q_s[128 + c + 1];
        }
    }
    float mx = fmaxf(l0, fmaxf(l1, l2));
    float e0 = expf(l0 - mx), e1 = expf(l1 - mx), e2 = expf(l2 - mx);
    float inv = 1.f / (e0 + e1 + e2);
    float a0 = e0 * inv, a1 = e1 * inv, a2 = e2 * inv;
    attn_out[r] = a0;
    attn_out[(size_t)N_TOK + r] = a1;
    attn_out[2 * (size_t)N_TOK + r] = a2;
    w_s[t * 4 + 0] = a0 + 1e-8f;
    w_s[t * 4 + 1] = a1 + 1e-8f;
    w_s[t * 4 + 2] = a2 + 1e-8f;
    {
        const uint4* vr = (const uint4*)(vb + r * 64);
        uint4* vl = (uint4*)(v_lds + t * 64);
#pragma unroll
        for (int i = 0; i < 8; ++i) vl[i] = vr[i];
    }
    __syncthreads();
    if (t < 192) {
        int s = t >> 6, c = t & 63;
        float part = 0.f;
        for (int r2 = 0; r2 < 256; ++r2) part += w_s[r2 * 4 + s] * bf2f(v_lds[r2 * 64 + c]);
        partials[(size_t)t * PSTRIDE + blockIdx.x] = part;
    } else if (t < 195) {
        int s = t - 192;
        float part = 0.f;
        for (int r2 = 0; r2 < 256; ++r2) part += w_s[r2 * 4 + s];
        partials[(size_t)t * PSTRIDE + blockIdx.x] = part;
    }
}

// ------- reduce: 195 blocks, one per column -------
__global__ __launch_bounds__(256) void reduce_kernel(const float* __restrict__ partials,
                                                     int nblk, float* __restrict__ reduced) {
    int col = blockIdx.x, t = threadIdx.x;
    float a = 0.f;
    for (int b = t; b < nblk; b += 256) a += partials[(size_t)col * PSTRIDE + b];
#pragma unroll
    for (int d = 1; d < 64; d <<= 1) a += __shfl_xor(a, d);
    __shared__ float ws_[4];
    if ((t & 63) == 0) ws_[t >> 6] = a;
    __syncthreads();
    if (t == 0) reduced[col] = (ws_[0] + ws_[1]) + (ws_[2] + ws_[3]);
}

// ------- update: GRU -> MLP -> (q | out slots) -------
__global__ __launch_bounds__(256) void update_kernel(
    const float* __restrict__ reduced,
    float* __restrict__ slots_ws, float* __restrict__ q_ws,
    const float* __restrict__ gbg_k, const float* __restrict__ gbg_rk, const float* __restrict__ gbg_bias,
    const float* __restrict__ gfg_k, const float* __restrict__ gfg_rk, const float* __restrict__ gfg_bias,
    const float* __restrict__ mbg_g, const float* __restrict__ mbg_b, const float* __restrict__ mbg_W1,
    const float* __restrict__ mbg_b1, const float* __restrict__ mbg_W2, const float* __restrict__ mbg_b2,
    const float* __restrict__ mfg_g, const float* __restrict__ mfg_b, const float* __restrict__ mfg_W1,
    const float* __restrict__ mfg_b1, const float* __restrict__ mfg_W2, const float* __restrict__ mfg_b2,
    const float* __restrict__ qbg_g, const float* __restrict__ qbg_b, const float* __restrict__ qbg_W,
    const float* __restrict__ qfg_g, const float* __restrict__ qfg_b, const float* __restrict__ qfg_W,
    int compute_q, float* __restrict__ out_slots) {
    __shared__ float upd[192], hslots[192], swv[3];
    __shared__ float xm[192], hm[192], gout[64], lnv[64], hid[64];
    int t = threadIdx.x;
    if (t < 192) { hslots[t] = slots_ws[t]; upd[t] = reduced[t]; }
    else if (t < 195) swv[t - 192] = reduced[t];
    __syncthreads();
    if (t < 192) upd[t] = upd[t] / swv[t >> 6];
    __syncthreads();

    for (int s = 0; s < 3; ++s) {
        const float* K = s ? gfg_k : gbg_k;
        const float* RK = s ? gfg_rk : gbg_rk;
        const float* BS = s ? gfg_bias : gbg_bias;
        if (t < 192) {
            float ax = BS[t], ah = BS[192 + t];
            const float* us = upd + s * 64;
            const float* hs = hslots + s * 64;
            for (int i = 0; i < 64; ++i) {
                ax += us[i] * K[i * 192 + t];
                ah += hs[i] * RK[i * 192 + t];
            }
            xm[t] = ax; hm[t] = ah;
        }
        __syncthreads();
        if (t < 64) {
            float z = sigmoidf_(xm[t] + hm[t]);
            float rg = sigmoidf_(xm[64 + t] + hm[64 + t]);
            float cand = tanhf(xm[128 + t] + rg * hm[128 + t]);
            gout[t] = z * hslots[s * 64 + t] + (1.f - z) * cand;
        }
        __syncthreads();
        const float* MG = s ? mfg_g : mbg_g;
        const float* MB = s ? mfg_b : mbg_b;
        const float* MW1 = s ? mfg_W1 : mbg_W1;
        const float* MB1 = s ? mfg_b1 : mbg_b1;
        const float* MW2 = s ? mfg_W2 : mbg_W2;
        const float* MB2 = s ? mfg_b2 : mbg_b2;
        if (t < 64) {
            float v = gout[t];
            float su = v, sq = v * v;
#pragma unroll
            for (int d = 1; d < 64; d <<= 1) { su += __shfl_xor(su, d); sq += __shfl_xor(sq, d); }
            float mean = su * (1.f / 64.f), var = sq * (1.f / 64.f) - mean * mean;
            float rstd = rsqrtf(var + 1e-3f);
            lnv[t] = (v - mean) * rstd * MG[t] + MB[t];
        }
        __syncthreads();
        if (t < 64) {
            float a = MB1[t];
            for (int i = 0; i < 64; ++i) a += lnv[i] * MW1[i * 64 + t];
            hid[t] = fmaxf(a, 0.f);
        }
        __syncthreads();
        if (t < 64) {
            float a = MB2[t];
            for (int i = 0; i < 64; ++i) a += hid[i] * MW2[i * 64 + t];
            hslots[s * 64 + t] = gout[t] + a;
        }
        __syncthreads();
    }
    if (t < 192) {
        slots_ws[t] = hslots[t];
        if (out_slots) out_slots[t] = hslots[t];
        if (compute_q) {
            int s = t >> 6, lane = t & 63;
            const float* g = s ? qfg_g : qbg_g;
            const float* b = s ? qfg_b : qbg_b;
            const float* W = s ? qfg_W : qbg_W;
            q_ws[t] = q_from_slot(hslots[t], g, b, W, lane);
        }
    }
}

extern "C" void kernel_launch(void* const* d_in, const int* in_sizes, int n_in,
                              void* d_out, int out_size, void* d_ws, size_t ws_size,
                              hipStream_t stream) {
    const float* x        = (const float*)d_in[0];
    const float* noise_fg = (const float*)d_in[1];
    const float* noise_bg = (const float*)d_in[2];
    const float* ln_g     = (const float*)d_in[3];
    const float* ln_b     = (const float*)d_in[4];
    const float* mu_fg    = (const float*)d_in[5];
    const float* ls_fg    = (const float*)d_in[6];
    const float* mu_bg    = (const float*)d_in[7];
    const float* ls_bg    = (const float*)d_in[8];
    const float* Wk       = (const float*)d_in[9];
    const float* Wv       = (const float*)d_in[10];
    const float* qfg_g    = (const float*)d_in[11];
    const float* qfg_b    = (const float*)d_in[12];
    const float* qfg_W    = (const float*)d_in[13];
    const float* qbg_g    = (const float*)d_in[14];
    const float* qbg_b    = (const float*)d_in[15];
    const float* qbg_W    = (const float*)d_in[16];
    const float* gfg_k    = (const float*)d_in[17];
    const float* gfg_rk   = (const float*)d_in[18];
    const float* gfg_bias = (const float*)d_in[19];
    const float* gbg_k    = (const float*)d_in[20];
    const float* gbg_rk   = (const float*)d_in[21];
    const float* gbg_bias = (const float*)d_in[22];
    const float* mfg_g    = (const float*)d_in[23];
    const float* mfg_b    = (const float*)d_in[24];
    const float* mfg_W1   = (const float*)d_in[25];
    const float* mfg_b1   = (const float*)d_in[26];
    const float* mfg_W2   = (const float*)d_in[27];
    const float* mfg_b2   = (const float*)d_in[28];
    const float* mbg_g    = (const float*)d_in[29];
    const float* mbg_b    = (const float*)d_in[30];
    const float* mbg_W1   = (const float*)d_in[31];
    const float* mbg_b1   = (const float*)d_in[32];
    const float* mbg_W2   = (const float*)d_in[33];
    const float* mbg_b2   = (const float*)d_in[34];

    char* ws = (char*)d_ws;
    unsigned short* Wt = (unsigned short*)ws;                  // 131072 B
    float* c12 = (float*)(ws + 131072);                        // 1024 B
    unsigned short* kb = (unsigned short*)(ws + 132096);       // 32 MB
    unsigned short* vb = kb + (size_t)N_TOK * 64;              // 32 MB
    char* ws2 = ws + 132096 + (size_t)2 * N_TOK * 64 * 2;
    float* slots_ws = (float*)ws2;                             // 192
    float* q_ws = slots_ws + 192;                              // 192
    float* reduced = q_ws + 192;                               // 256 (padded)
    float* partials = reduced + 256;                           // 195 * PSTRIDE

    float* out = (float*)d_out;

    wt_init_kernel<<<dim3(129), dim3(256), 0, stream>>>(
        Wk, Wv, ln_g, ln_b, Wt, c12,
        noise_fg, noise_bg, mu_fg, ls_fg, mu_bg, ls_bg,
        qbg_g, qbg_b, qbg_W, qfg_g, qfg_b, qfg_W, slots_ws, q_ws);
    phaseA_kernel<<<dim3(NBLK_A), dim3(512), 0, stream>>>(x, Wt, c12, q_ws, kb, vb, partials);
    reduce_kernel<<<dim3(195), dim3(256), 0, stream>>>(partials, NBLK_A * 4, reduced);
    update_kernel<<<dim3(1), dim3(256), 0, stream>>>(reduced, slots_ws, q_ws,
        gbg_k, gbg_rk, gbg_bias, gfg_k, gfg_rk, gfg_bias,
        mbg_g, mbg_b, mbg_W1, mbg_b1, mbg_W2, mbg_b2,
        mfg_g, mfg_b, mfg_W1, mfg_b1, mfg_W2, mfg_b2,
        qbg_g, qbg_b, qbg_W, qfg_g, qfg_b, qfg_W, 1, (float*)nullptr);
    iter2_kernel<<<dim3(NBLK_I2), dim3(256), 0, stream>>>(kb, vb, q_ws, out + 192, partials);
    reduce_kernel<<<dim3(195), dim3(256), 0, stream>>>(partials, NBLK_I2, reduced);
    update_kernel<<<dim3(1), dim3(256), 0, stream>>>(reduced, slots_ws, q_ws,
        gbg_k, gbg_rk, gbg_bias, gfg_k, gfg_rk, gfg_bias,
        mbg_g, mbg_b, mbg_W1, mbg_b1, mbg_W2, mbg_b2,
        mfg_g, mfg_b, mfg_W1, mfg_b1, mfg_W2, mfg_b2,
        qbg_g, qbg_b, qbg_W, qfg_g, qfg_b, qfg_W, 0, out);
}

// Round 9
// 271.985 us; speedup vs baseline: 1.5013x; 1.0272x over previous
//
#include <hip/hip_runtime.h>
#include <hip/hip_bf16.h>

// SlotAttention fused implementation, round 9.
// = round-2 structure exactly, with hardware v_cvt_pk_bf16_f32 replacing the
// 5-op manual bf16 pack in phaseA (P1 staging + P4 k/v store).
// Theory: phaseA was VALU-bound on software bf16 conversion (~130us/CU).

#define N_TOK 262144
#define CIN 512
#define TILE_M 64
#define NBLK_A 512
#define NBLK_I2 1024
#define PSTRIDE 1024

typedef __attribute__((ext_vector_type(8))) short short8;
typedef __attribute__((ext_vector_type(4))) float f32x4;

__device__ __forceinline__ unsigned short f2bf(float f) {
    union { float f; unsigned u; } v; v.f = f;
    unsigned r = v.u + 0x7FFFu + ((v.u >> 16) & 1u);
    return (unsigned short)(r >> 16);
}
// hardware packed conversion: D[15:0]=bf16(a), D[31:16]=bf16(b), RNE
__device__ __forceinline__ unsigned pkbf(float a, float b) {
    unsigned r;
    asm("v_cvt_pk_bf16_f32 %0, %1, %2" : "=v"(r) : "v"(a), "v"(b));
    return r;
}
__device__ __forceinline__ float bf2f(unsigned short u) {
    union { unsigned u; float f; } v; v.u = ((unsigned)u) << 16;
    return v.f;
}
__device__ __forceinline__ float sigmoidf_(float x) { return 1.f / (1.f + expf(-x)); }

__device__ __forceinline__ float q_from_slot(float v, const float* __restrict__ g,
                                             const float* __restrict__ b,
                                             const float* __restrict__ W, int lane) {
    float s = v, s2 = v * v;
#pragma unroll
    for (int d = 1; d < 64; d <<= 1) { s += __shfl_xor(s, d); s2 += __shfl_xor(s2, d); }
    float mean = s * (1.f / 64.f);
    float var = s2 * (1.f / 64.f) - mean * mean;
    float rstd = rsqrtf(var + 1e-3f);
    float hl = (v - mean) * rstd * g[lane] + b[lane];
    float acc = 0.f;
    for (int i = 0; i < 64; ++i) acc += __shfl(hl, i) * W[i * 64 + lane];
    return acc * 0.125f;
}

// ------- wt_init: blocks 0..127 build Wt (g*W bf16, transposed) + c1/c2; block 128 = slot init -------
__global__ __launch_bounds__(256) void wt_init_kernel(
    const float* __restrict__ Wk, const float* __restrict__ Wv,
    const float* __restrict__ ln_g, const float* __restrict__ ln_b,
    unsigned short* __restrict__ Wt, float* __restrict__ c12,
    const float* __restrict__ noise_fg, const float* __restrict__ noise_bg,
    const float* __restrict__ mu_fg, const float* __restrict__ ls_fg,
    const float* __restrict__ mu_bg, const float* __restrict__ ls_bg,
    const float* __restrict__ qbg_g, const float* __restrict__ qbg_b, const float* __restrict__ qbg_W,
    const float* __restrict__ qfg_g, const float* __restrict__ qfg_b, const float* __restrict__ qfg_W,
    float* __restrict__ slots_ws, float* __restrict__ q_ws) {
    int t = threadIdx.x;
    if (blockIdx.x < 128) {
        int j = blockIdx.x;
        const float* W = (j < 64) ? Wk : Wv;
        int jc = j & 63;
        float c1 = 0.f, c2 = 0.f;
        for (int i = t; i < 512; i += 256) {
            float wv = W[i * 64 + jc];
            float g = ln_g[i], b = ln_b[i];
            c1 += g * wv; c2 += b * wv;
            Wt[(size_t)j * 512 + i] = f2bf(g * wv);
        }
        __shared__ float s1[4], s2[4];
#pragma unroll
        for (int d = 1; d < 64; d <<= 1) { c1 += __shfl_xor(c1, d); c2 += __shfl_xor(c2, d); }
        if ((t & 63) == 0) { s1[t >> 6] = c1; s2[t >> 6] = c2; }
        __syncthreads();
        if (t == 0) {
            c12[j] = (s1[0] + s1[1]) + (s1[2] + s1[3]);
            c12[128 + j] = (s2[0] + s2[1]) + (s2[2] + s2[3]);
        }
    } else {
        if (t < 192) {
            int s = t >> 6, c = t & 63;
            float v = (s == 0) ? (mu_bg[c] + expf(ls_bg[c]) * noise_bg[c])
                               : (mu_fg[c] + expf(ls_fg[c]) * noise_fg[(s - 1) * 64 + c]);
            slots_ws[t] = v;
            const float* g = s ? qfg_g : qbg_g;
            const float* b = s ? qfg_b : qbg_b;
            const float* W = s ? qfg_W : qbg_W;
            q_ws[t] = q_from_slot(v, g, b, W, c);
        }
    }
}

// ------- phase A: stats + raw-x bf16 stage (HW cvt_pk) + MFMA + fixup + attn partials -------
__global__ __launch_bounds__(256, 2) void phaseA_kernel(
    const float* __restrict__ x, const unsigned short* __restrict__ Wt,
    const float* __restrict__ c12, const float* __restrict__ qv,
    unsigned short* __restrict__ kb, unsigned short* __restrict__ vb,
    float* __restrict__ partials) {
    __shared__ unsigned short SA[TILE_M * CIN];  // 64KB bf16 (swizzled); aliased as kvf f32 after MFMA
    __shared__ float q_s[192];
    __shared__ float w_s[64 * 4];
    __shared__ float2 rowstat[64];  // (rstd, mean*rstd)
    float* kvf = (float*)SA;        // [64][130]

    const int t = threadIdx.x;
    const int lane = t & 63;
    const int w = t >> 6;

    if (t < 192) q_s[t] = qv[t];

    short8 bfrag[16][2];
    float c1r[2], c2r[2];
#pragma unroll
    for (int nt = 0; nt < 2; ++nt) {
        int col = w * 32 + nt * 16 + (lane & 15);
        c1r[nt] = c12[col];
        c2r[nt] = c12[128 + col];
#pragma unroll
        for (int kk = 0; kk < 16; ++kk) {
            int off = kk * 32 + ((lane >> 4) << 3);
            bfrag[kk][nt] = *(const short8*)(Wt + (size_t)col * 512 + off);
        }
    }

    float upd_acc = 0.f;
    float sw_acc = 0.f;

    for (int tile = blockIdx.x; tile < N_TOK / TILE_M; tile += NBLK_A) {
        const size_t row0 = (size_t)tile * TILE_M;
        __syncthreads();

        // ---- P1: 8 lanes per row -> sums + bf16 stage (HW packed cvt) ----
#pragma unroll
        for (int p = 0; p < 2; ++p) {
            int r = w * 16 + p * 8 + (lane >> 3);
            int c8 = lane & 7;
            const float4* xr = (const float4*)(x + (row0 + r) * CIN) + c8 * 16;
            char* rowbase = (char*)SA + r * 1024;
            int bb = c8 * 128;
            int sw = (r & 7) << 4;
            float s = 0.f, s2 = 0.f;
#pragma unroll
            for (int i = 0; i < 8; ++i) {
                float4 a = xr[2 * i];
                float4 b = xr[2 * i + 1];
                s += (a.x + a.y) + (a.z + a.w) + (b.x + b.y) + (b.z + b.w);
                s2 = fmaf(a.x, a.x, s2); s2 = fmaf(a.y, a.y, s2);
                s2 = fmaf(a.z, a.z, s2); s2 = fmaf(a.w, a.w, s2);
                s2 = fmaf(b.x, b.x, s2); s2 = fmaf(b.y, b.y, s2);
                s2 = fmaf(b.z, b.z, s2); s2 = fmaf(b.w, b.w, s2);
                uint4 o;
                o.x = pkbf(a.x, a.y); o.y = pkbf(a.z, a.w);
                o.z = pkbf(b.x, b.y); o.w = pkbf(b.z, b.w);
                *(uint4*)(rowbase + ((bb + i * 16) ^ sw)) = o;
            }
#pragma unroll
            for (int d = 1; d < 8; d <<= 1) { s += __shfl_xor(s, d); s2 += __shfl_xor(s2, d); }
            if (c8 == 0) {
                float mean = s * (1.f / 512.f);
                float var = s2 * (1.f / 512.f) - mean * mean;
                float rstd = rsqrtf(var + 1e-3f);
                rowstat[r] = make_float2(rstd, mean * rstd);
            }
        }
        __syncthreads();

        // ---- P2: MFMA ----
        f32x4 acc[4][2];
#pragma unroll
        for (int m = 0; m < 4; ++m) {
            acc[m][0] = (f32x4){0.f, 0.f, 0.f, 0.f};
            acc[m][1] = (f32x4){0.f, 0.f, 0.f, 0.f};
        }
#pragma unroll
        for (int kk = 0; kk < 16; ++kk) {
#pragma unroll
            for (int m = 0; m < 4; ++m) {
                int row = m * 16 + (lane & 15);
                int boff = (kk * 64 + ((lane >> 4) << 4)) ^ ((row & 7) << 4);
                short8 af = *(const short8*)((const char*)SA + row * 1024 + boff);
                acc[m][0] = __builtin_amdgcn_mfma_f32_16x16x32_bf16(af, bfrag[kk][0], acc[m][0], 0, 0, 0);
                acc[m][1] = __builtin_amdgcn_mfma_f32_16x16x32_bf16(af, bfrag[kk][1], acc[m][1], 0, 0, 0);
            }
        }
        __syncthreads();

        // ---- P3: affine fixup + write kvf ----
        float2 rs[16];
#pragma unroll
        for (int m = 0; m < 4; ++m)
#pragma unroll
            for (int j = 0; j < 4; ++j)
                rs[m * 4 + j] = rowstat[m * 16 + ((lane >> 4) << 2) + j];
#pragma unroll
        for (int m = 0; m < 4; ++m)
#pragma unroll
            for (int n = 0; n < 2; ++n)
#pragma unroll
                for (int j = 0; j < 4; ++j) {
                    int row = m * 16 + ((lane >> 4) << 2) + j;
                    int col = w * 32 + n * 16 + (lane & 15);
                    float val = fmaf(rs[m * 4 + j].x, acc[m][n][j],
                                     fmaf(-rs[m * 4 + j].y, c1r[n], c2r[n]));
                    kvf[row * 130 + col] = val;
                }
        __syncthreads();

        // ---- P4: bf16 store of k,v (HW packed cvt) + wave0 softmax weights ----
        {
            int r = t >> 2, q4 = t & 3;
            unsigned short* dst = ((q4 < 2) ? kb : vb) + (row0 + r) * 64 + (q4 & 1) * 32;
            const float* src = &kvf[r * 130 + q4 * 32];
#pragma unroll
            for (int j = 0; j < 32; j += 8) {
                float2 p0 = *(const float2*)(src + j);
                float2 p1 = *(const float2*)(src + j + 2);
                float2 p2 = *(const float2*)(src + j + 4);
                float2 p3 = *(const float2*)(src + j + 6);
                uint4 o;
                o.x = pkbf(p0.x, p0.y);
                o.y = pkbf(p1.x, p1.y);
                o.z = pkbf(p2.x, p2.y);
                o.w = pkbf(p3.x, p3.y);
                *(uint4*)(dst + j) = o;
            }
        }
        if (t < 64) {
            int r = t;
            float l0 = 0.f, l1 = 0.f, l2 = 0.f;
#pragma unroll 8
            for (int c = 0; c < 64; c += 2) {
                float2 kv2 = *(const float2*)&kvf[r * 130 + c];
                l0 += kv2.x * q_s[c] + kv2.y * q_s[c + 1];
                l1 += kv2.x * q_s[64 + c] + kv2.y * q_s[64 + c + 1];
                l2 += kv2.x * q_s[128 + c] + kv2.y * q_s[128 + c + 1];
            }
            float mx = fmaxf(l0, fmaxf(l1, l2));
            float e0 = expf(l0 - mx), e1 = expf(l1 - mx), e2 = expf(l2 - mx);
            float inv = 1.f / (e0 + e1 + e2);
            w_s[r * 4 + 0] = e0 * inv + 1e-8f;
            w_s[r * 4 + 1] = e1 * inv + 1e-8f;
            w_s[r * 4 + 2] = e2 * inv + 1e-8f;
        }
        __syncthreads();

        // ---- P5: outer-product partial accumulate ----
        if (t < 192) {
            int s = t >> 6, c = t & 63;
            float a = 0.f;
            for (int r = 0; r < 64; ++r) a += w_s[r * 4 + s] * kvf[r * 130 + 64 + c];
            upd_acc += a;
        } else if (t < 195) {
            int s = t - 192;
            float a = 0.f;
            for (int r = 0; r < 64; ++r) a += w_s[r * 4 + s];
            sw_acc += a;
        }
    }
    if (t < 192) partials[(size_t)t * PSTRIDE + blockIdx.x] = upd_acc;
    else if (t < 195) partials[(size_t)t * PSTRIDE + blockIdx.x] = sw_acc;
}

// ------- iter 2: attention with q2, writes attn.T + partials (transposed) -------
__global__ __launch_bounds__(256) void iter2_kernel(
    const unsigned short* __restrict__ kb, const unsigned short* __restrict__ vb,
    const float* __restrict__ qv, float* __restrict__ attn_out, float* __restrict__ partials) {
    __shared__ float q_s[192];
    __shared__ float w_s[256 * 4];
    __shared__ unsigned short v_lds[256 * 64];
    int t = threadIdx.x;
    if (t < 192) q_s[t] = qv[t];
    __syncthreads();
    size_t r = (size_t)blockIdx.x * 256 + t;
    const unsigned short* krow = kb + r * 64;
    float l0 = 0.f, l1 = 0.f, l2 = 0.f;
#pragma unroll
    for (int i = 0; i < 8; ++i) {
        uint4 u = *(const uint4*)(krow + i * 8);
        unsigned uu[4] = {u.x, u.y, u.z, u.w};
#pragma unroll
        for (int p = 0; p < 4; ++p) {
            float fa = bf2f((unsigned short)(uu[p] & 0xffffu));
            float fb = bf2f((unsigned short)(uu[p] >> 16));
            int c = i * 8 + p * 2;
            l0 += fa * q_s[c] + fb * q_s[c + 1];
            l1 += fa * q_s[64 + c] + fb * q_s[64 + c + 1];
            l2 += fa * q_s[128 + c] + fb * q_s[128 + c + 1];
        }
    }
    float mx = fmaxf(l0, fmaxf(l1, l2));
    float e0 = expf(l0 - mx), e1 = expf(l1 - mx), e2 = expf(l2 - mx);
    float inv = 1.f / (e0 + e1 + e2);
    float a0 = e0 * inv, a1 = e1 * inv, a2 = e2 * inv;
    attn_out[r] = a0;
    attn_out[(size_t)N_TOK + r] = a1;
    attn_out[2 * (size_t)N_TOK + r] = a2;
    w_s[t * 4 + 0] = a0 + 1e-8f;
    w_s[t * 4 + 1] = a1 + 1e-8f;
    w_s[t * 4 + 2] = a2 + 1e-8f;
    {
        const uint4* vr = (const uint4*)(vb + r * 64);
        uint4* vl = (uint4*)(v_lds + t * 64);
#pragma unroll
        for (int i = 0; i < 8; ++i) vl[i] = vr[i];
    }
    __syncthreads();
    if (t < 192) {
        int s = t >> 6, c = t & 63;
        float part = 0.f;
        for (int r2 = 0; r2 < 256; ++r2) part += w_s[r2 * 4 + s] * bf2f(v_lds[r2 * 64 + c]);
        partials[(size_t)t * PSTRIDE + blockIdx.x] = part;
    } else if (t < 195) {
        int s = t - 192;
        float part = 0.f;
        for (int r2 = 0; r2 < 256; ++r2) part += w_s[r2 * 4 + s];
        partials[(size_t)t * PSTRIDE + blockIdx.x] = part;
    }
}

// ------- reduce: 195 blocks, one per column -------
__global__ __launch_bounds__(256) void reduce_kernel(const float* __restrict__ partials,
                                                     int nblk, float* __restrict__ reduced) {
    int col = blockIdx.x, t = threadIdx.x;
    float a = 0.f;
    for (int b = t; b < nblk; b += 256) a += partials[(size_t)col * PSTRIDE + b];
#pragma unroll
    for (int d = 1; d < 64; d <<= 1) a += __shfl_xor(a, d);
    __shared__ float ws_[4];
    if ((t & 63) == 0) ws_[t >> 6] = a;
    __syncthreads();
    if (t == 0) reduced[col] = (ws_[0] + ws_[1]) + (ws_[2] + ws_[3]);
}

// ------- update: GRU -> MLP -> (q | out slots) -------
__global__ __launch_bounds__(256) void update_kernel(
    const float* __restrict__ reduced,
    float* __restrict__ slots_ws, float* __restrict__ q_ws,
    const float* __restrict__ gbg_k, const float* __restrict__ gbg_rk, const float* __restrict__ gbg_bias,
    const float* __restrict__ gfg_k, const float* __restrict__ gfg_rk, const float* __restrict__ gfg_bias,
    const float* __restrict__ mbg_g, const float* __restrict__ mbg_b, const float* __restrict__ mbg_W1,
    const float* __restrict__ mbg_b1, const float* __restrict__ mbg_W2, const float* __restrict__ mbg_b2,
    const float* __restrict__ mfg_g, const float* __restrict__ mfg_b, const float* __restrict__ mfg_W1,
    const float* __restrict__ mfg_b1, const float* __restrict__ mfg_W2, const float* __restrict__ mfg_b2,
    const float* __restrict__ qbg_g, const float* __restrict__ qbg_b, const float* __restrict__ qbg_W,
    const float* __restrict__ qfg_g, const float* __restrict__ qfg_b, const float* __restrict__ qfg_W,
    int compute_q, float* __restrict__ out_slots) {
    __shared__ float upd[192], hslots[192], swv[3];
    __shared__ float xm[192], hm[192], gout[64], lnv[64], hid[64];
    int t = threadIdx.x;
    if (t < 192) { hslots[t] = slots_ws[t]; upd[t] = reduced[t]; }
    else if (t < 195) swv[t - 192] = reduced[t];
    __syncthreads();
    if (t < 192) upd[t] = upd[t] / swv[t >> 6];
    __syncthreads();

    for (int s = 0; s < 3; ++s) {
        const float* K = s ? gfg_k : gbg_k;
        const float* RK = s ? gfg_rk : gbg_rk;
        const float* BS = s ? gfg_bias : gbg_bias;
        if (t < 192) {
            float ax = BS[t], ah = BS[192 + t];
            const float* us = upd + s * 64;
            const float* hs = hslots + s * 64;
            for (int i = 0; i < 64; ++i) {
                ax += us[i] * K[i * 192 + t];
                ah += hs[i] * RK[i * 192 + t];
            }
            xm[t] = ax; hm[t] = ah;
        }
        __syncthreads();
        if (t < 64) {
            float z = sigmoidf_(xm[t] + hm[t]);
            float rg = sigmoidf_(xm[64 + t] + hm[64 + t]);
            float cand = tanhf(xm[128 + t] + rg * hm[128 + t]);
            gout[t] = z * hslots[s * 64 + t] + (1.f - z) * cand;
        }
        __syncthreads();
        const float* MG = s ? mfg_g : mbg_g;
        const float* MB = s ? mfg_b : mbg_b;
        const float* MW1 = s ? mfg_W1 : mbg_W1;
        const float* MB1 = s ? mfg_b1 : mbg_b1;
        const float* MW2 = s ? mfg_W2 : mbg_W2;
        const float* MB2 = s ? mfg_b2 : mbg_b2;
        if (t < 64) {
            float v = gout[t];
            float su = v, sq = v * v;
#pragma unroll
            for (int d = 1; d < 64; d <<= 1) { su += __shfl_xor(su, d); sq += __shfl_xor(sq, d); }
            float mean = su * (1.f / 64.f), var = sq * (1.f / 64.f) - mean * mean;
            float rstd = rsqrtf(var + 1e-3f);
            lnv[t] = (v - mean) * rstd * MG[t] + MB[t];
        }
        __syncthreads();
        if (t < 64) {
            float a = MB1[t];
            for (int i = 0; i < 64; ++i) a += lnv[i] * MW1[i * 64 + t];
            hid[t] = fmaxf(a, 0.f);
        }
        __syncthreads();
        if (t < 64) {
            float a = MB2[t];
            for (int i = 0; i < 64; ++i) a += hid[i] * MW2[i * 64 + t];
            hslots[s * 64 + t] = gout[t] + a;
        }
        __syncthreads();
    }
    if (t < 192) {
        slots_ws[t] = hslots[t];
        if (out_slots) out_slots[t] = hslots[t];
        if (compute_q) {
            int s = t >> 6, lane = t & 63;
            const float* g = s ? qfg_g : qbg_g;
            const float* b = s ? qfg_b : qbg_b;
            const float* W = s ? qfg_W : qbg_W;
            q_ws[t] = q_from_slot(hslots[t], g, b, W, lane);
        }
    }
}

extern "C" void kernel_launch(void* const* d_in, const int* in_sizes, int n_in,
                              void* d_out, int out_size, void* d_ws, size_t ws_size,
                              hipStream_t stream) {
    const float* x        = (const float*)d_in[0];
    const float* noise_fg = (const float*)d_in[1];
    const float* noise_bg = (const float*)d_in[2];
    const float* ln_g     = (const float*)d_in[3];
    const float* ln_b     = (const float*)d_in[4];
    const float* mu_fg    = (const float*)d_in[5];
    const float* ls_fg    = (const float*)d_in[6];
    const float* mu_bg    = (const float*)d_in[7];
    const float* ls_bg    = (const float*)d_in[8];
    const float* Wk       = (const float*)d_in[9];
    const float* Wv       = (const float*)d_in[10];
    const float* qfg_g    = (const float*)d_in[11];
    const float* qfg_b    = (const float*)d_in[12];
    const float* qfg_W    = (const float*)d_in[13];
    const float* qbg_g    = (const float*)d_in[14];
    const float* qbg_b    = (const float*)d_in[15];
    const float* qbg_W    = (const float*)d_in[16];
    const float* gfg_k    = (const float*)d_in[17];
    const float* gfg_rk   = (const float*)d_in[18];
    const float* gfg_bias = (const float*)d_in[19];
    const float* gbg_k    = (const float*)d_in[20];
    const float* gbg_rk   = (const float*)d_in[21];
    const float* gbg_bias = (const float*)d_in[22];
    const float* mfg_g    = (const float*)d_in[23];
    const float* mfg_b    = (const float*)d_in[24];
    const float* mfg_W1   = (const float*)d_in[25];
    const float* mfg_b1   = (const float*)d_in[26];
    const float* mfg_W2   = (const float*)d_in[27];
    const float* mfg_b2   = (const float*)d_in[28];
    const float* mbg_g    = (const float*)d_in[29];
    const float* mbg_b    = (const float*)d_in[30];
    const float* mbg_W1   = (const float*)d_in[31];
    const float* mbg_b1   = (const float*)d_in[32];
    const float* mbg_W2   = (const float*)d_in[33];
    const float* mbg_b2   = (const float*)d_in[34];

    char* ws = (char*)d_ws;
    unsigned short* Wt = (unsigned short*)ws;                  // 131072 B
    float* c12 = (float*)(ws + 131072);                        // 1024 B
    unsigned short* kb = (unsigned short*)(ws + 132096);       // 32 MB
    unsigned short* vb = kb + (size_t)N_TOK * 64;              // 32 MB
    char* ws2 = ws + 132096 + (size_t)2 * N_TOK * 64 * 2;
    float* slots_ws = (float*)ws2;                             // 192
    float* q_ws = slots_ws + 192;                              // 192
    float* reduced = q_ws + 192;                               // 256 (padded)
    float* partials = reduced + 256;                           // 195 * PSTRIDE

    float* out = (float*)d_out;

    wt_init_kernel<<<dim3(129), dim3(256), 0, stream>>>(
        Wk, Wv, ln_g, ln_b, Wt, c12,
        noise_fg, noise_bg, mu_fg, ls_fg, mu_bg, ls_bg,
        qbg_g, qbg_b, qbg_W, qfg_g, qfg_b, qfg_W, slots_ws, q_ws);
    phaseA_kernel<<<dim3(NBLK_A), dim3(256), 0, stream>>>(x, Wt, c12, q_ws, kb, vb, partials);
    reduce_kernel<<<dim3(195), dim3(256), 0, stream>>>(partials, NBLK_A, reduced);
    update_kernel<<<dim3(1), dim3(256), 0, stream>>>(reduced, slots_ws, q_ws,
        gbg_k, gbg_rk, gbg_bias, gfg_k, gfg_rk, gfg_bias,
        mbg_g, mbg_b, mbg_W1, mbg_b1, mbg_W2, mbg_b2,
        mfg_g, mfg_b, mfg_W1, mfg_b1, mfg_W2, mfg_b2,
        qbg_g, qbg_b, qbg_W, qfg_g, qfg_b, qfg_W, 1, (float*)nullptr);
    iter2_kernel<<<dim3(NBLK_I2), dim3(256), 0, stream>>>(kb, vb, q_ws, out + 192, partials);
    reduce_kernel<<<dim3(195), dim3(256), 0, stream>>>(partials, NBLK_I2, reduced);
    update_kernel<<<dim3(1), dim3(256), 0, stream>>>(reduced, slots_ws, q_ws,
        gbg_k, gbg_rk, gbg_bias, gfg_k, gfg_rk, gfg_bias,
        mbg_g, mbg_b, mbg_W1, mbg_b1, mbg_W2, mbg_b2,
        mfg_g, mfg_b, mfg_W1, mfg_b1, mfg_W2, mfg_b2,
        qbg_g, qbg_b, qbg_W, qfg_g, qfg_b, qfg_W, 0, out);
}

// Round 10
// 238.379 us; speedup vs baseline: 1.7129x; 1.1410x over previous
//
#include <hip/hip_runtime.h>
#include <hip/hip_bf16.h>

// SlotAttention fused implementation, round 10.
// = round-2 structure exactly; bf16 conversion via scalar __float2bfloat16
// casts (compiler auto-pairs into v_cvt_pk_bf16_f32 and keeps scheduling
// freedom — per m240 scalar cast beats both manual bit-twiddle and hand asm).

#define N_TOK 262144
#define CIN 512
#define TILE_M 64
#define NBLK_A 512
#define NBLK_I2 1024
#define PSTRIDE 1024

typedef __attribute__((ext_vector_type(8))) short short8;
typedef __attribute__((ext_vector_type(4))) float f32x4;

__device__ __forceinline__ unsigned short f2bf(float f) {
    __hip_bfloat16 h = __float2bfloat16(f);
    union { __hip_bfloat16 h; unsigned short u; } v; v.h = h;
    return v.u;
}
__device__ __forceinline__ unsigned pkbf(float a, float b) {
    return (unsigned)f2bf(a) | ((unsigned)f2bf(b) << 16);
}
__device__ __forceinline__ float bf2f(unsigned short u) {
    union { unsigned u; float f; } v; v.u = ((unsigned)u) << 16;
    return v.f;
}
__device__ __forceinline__ float sigmoidf_(float x) { return 1.f / (1.f + expf(-x)); }

__device__ __forceinline__ float q_from_slot(float v, const float* __restrict__ g,
                                             const float* __restrict__ b,
                                             const float* __restrict__ W, int lane) {
    float s = v, s2 = v * v;
#pragma unroll
    for (int d = 1; d < 64; d <<= 1) { s += __shfl_xor(s, d); s2 += __shfl_xor(s2, d); }
    float mean = s * (1.f / 64.f);
    float var = s2 * (1.f / 64.f) - mean * mean;
    float rstd = rsqrtf(var + 1e-3f);
    float hl = (v - mean) * rstd * g[lane] + b[lane];
    float acc = 0.f;
    for (int i = 0; i < 64; ++i) acc += __shfl(hl, i) * W[i * 64 + lane];
    return acc * 0.125f;
}

// ------- wt_init: blocks 0..127 build Wt (g*W bf16, transposed) + c1/c2; block 128 = slot init -------
__global__ __launch_bounds__(256) void wt_init_kernel(
    const float* __restrict__ Wk, const float* __restrict__ Wv,
    const float* __restrict__ ln_g, const float* __restrict__ ln_b,
    unsigned short* __restrict__ Wt, float* __restrict__ c12,
    const float* __restrict__ noise_fg, const float* __restrict__ noise_bg,
    const float* __restrict__ mu_fg, const float* __restrict__ ls_fg,
    const float* __restrict__ mu_bg, const float* __restrict__ ls_bg,
    const float* __restrict__ qbg_g, const float* __restrict__ qbg_b, const float* __restrict__ qbg_W,
    const float* __restrict__ qfg_g, const float* __restrict__ qfg_b, const float* __restrict__ qfg_W,
    float* __restrict__ slots_ws, float* __restrict__ q_ws) {
    int t = threadIdx.x;
    if (blockIdx.x < 128) {
        int j = blockIdx.x;
        const float* W = (j < 64) ? Wk : Wv;
        int jc = j & 63;
        float c1 = 0.f, c2 = 0.f;
        for (int i = t; i < 512; i += 256) {
            float wv = W[i * 64 + jc];
            float g = ln_g[i], b = ln_b[i];
            c1 += g * wv; c2 += b * wv;
            Wt[(size_t)j * 512 + i] = f2bf(g * wv);
        }
        __shared__ float s1[4], s2[4];
#pragma unroll
        for (int d = 1; d < 64; d <<= 1) { c1 += __shfl_xor(c1, d); c2 += __shfl_xor(c2, d); }
        if ((t & 63) == 0) { s1[t >> 6] = c1; s2[t >> 6] = c2; }
        __syncthreads();
        if (t == 0) {
            c12[j] = (s1[0] + s1[1]) + (s1[2] + s1[3]);
            c12[128 + j] = (s2[0] + s2[1]) + (s2[2] + s2[3]);
        }
    } else {
        if (t < 192) {
            int s = t >> 6, c = t & 63;
            float v = (s == 0) ? (mu_bg[c] + expf(ls_bg[c]) * noise_bg[c])
                               : (mu_fg[c] + expf(ls_fg[c]) * noise_fg[(s - 1) * 64 + c]);
            slots_ws[t] = v;
            const float* g = s ? qfg_g : qbg_g;
            const float* b = s ? qfg_b : qbg_b;
            const float* W = s ? qfg_W : qbg_W;
            q_ws[t] = q_from_slot(v, g, b, W, c);
        }
    }
}

// ------- phase A: stats + raw-x bf16 stage + MFMA + affine fixup + iter1 attn partials -------
__global__ __launch_bounds__(256, 2) void phaseA_kernel(
    const float* __restrict__ x, const unsigned short* __restrict__ Wt,
    const float* __restrict__ c12, const float* __restrict__ qv,
    unsigned short* __restrict__ kb, unsigned short* __restrict__ vb,
    float* __restrict__ partials) {
    __shared__ unsigned short SA[TILE_M * CIN];  // 64KB bf16 (swizzled); aliased as kvf f32 after MFMA
    __shared__ float q_s[192];
    __shared__ float w_s[64 * 4];
    __shared__ float2 rowstat[64];  // (rstd, mean*rstd)
    float* kvf = (float*)SA;        // [64][130]

    const int t = threadIdx.x;
    const int lane = t & 63;
    const int w = t >> 6;

    if (t < 192) q_s[t] = qv[t];

    short8 bfrag[16][2];
    float c1r[2], c2r[2];
#pragma unroll
    for (int nt = 0; nt < 2; ++nt) {
        int col = w * 32 + nt * 16 + (lane & 15);
        c1r[nt] = c12[col];
        c2r[nt] = c12[128 + col];
#pragma unroll
        for (int kk = 0; kk < 16; ++kk) {
            int off = kk * 32 + ((lane >> 4) << 3);
            bfrag[kk][nt] = *(const short8*)(Wt + (size_t)col * 512 + off);
        }
    }

    float upd_acc = 0.f;
    float sw_acc = 0.f;

    for (int tile = blockIdx.x; tile < N_TOK / TILE_M; tile += NBLK_A) {
        const size_t row0 = (size_t)tile * TILE_M;
        __syncthreads();

        // ---- P1: 8 lanes per row -> sums + bf16 stage ----
#pragma unroll
        for (int p = 0; p < 2; ++p) {
            int r = w * 16 + p * 8 + (lane >> 3);
            int c8 = lane & 7;
            const float4* xr = (const float4*)(x + (row0 + r) * CIN) + c8 * 16;
            char* rowbase = (char*)SA + r * 1024;
            int bb = c8 * 128;
            int sw = (r & 7) << 4;
            float s = 0.f, s2 = 0.f;
#pragma unroll
            for (int i = 0; i < 8; ++i) {
                float4 a = xr[2 * i];
                float4 b = xr[2 * i + 1];
                s += (a.x + a.y) + (a.z + a.w) + (b.x + b.y) + (b.z + b.w);
                s2 = fmaf(a.x, a.x, s2); s2 = fmaf(a.y, a.y, s2);
                s2 = fmaf(a.z, a.z, s2); s2 = fmaf(a.w, a.w, s2);
                s2 = fmaf(b.x, b.x, s2); s2 = fmaf(b.y, b.y, s2);
                s2 = fmaf(b.z, b.z, s2); s2 = fmaf(b.w, b.w, s2);
                uint4 o;
                o.x = pkbf(a.x, a.y); o.y = pkbf(a.z, a.w);
                o.z = pkbf(b.x, b.y); o.w = pkbf(b.z, b.w);
                *(uint4*)(rowbase + ((bb + i * 16) ^ sw)) = o;
            }
#pragma unroll
            for (int d = 1; d < 8; d <<= 1) { s += __shfl_xor(s, d); s2 += __shfl_xor(s2, d); }
            if (c8 == 0) {
                float mean = s * (1.f / 512.f);
                float var = s2 * (1.f / 512.f) - mean * mean;
                float rstd = rsqrtf(var + 1e-3f);
                rowstat[r] = make_float2(rstd, mean * rstd);
            }
        }
        __syncthreads();

        // ---- P2: MFMA ----
        f32x4 acc[4][2];
#pragma unroll
        for (int m = 0; m < 4; ++m) {
            acc[m][0] = (f32x4){0.f, 0.f, 0.f, 0.f};
            acc[m][1] = (f32x4){0.f, 0.f, 0.f, 0.f};
        }
#pragma unroll
        for (int kk = 0; kk < 16; ++kk) {
#pragma unroll
            for (int m = 0; m < 4; ++m) {
                int row = m * 16 + (lane & 15);
                int boff = (kk * 64 + ((lane >> 4) << 4)) ^ ((row & 7) << 4);
                short8 af = *(const short8*)((const char*)SA + row * 1024 + boff);
                acc[m][0] = __builtin_amdgcn_mfma_f32_16x16x32_bf16(af, bfrag[kk][0], acc[m][0], 0, 0, 0);
                acc[m][1] = __builtin_amdgcn_mfma_f32_16x16x32_bf16(af, bfrag[kk][1], acc[m][1], 0, 0, 0);
            }
        }
        __syncthreads();

        // ---- P3: affine fixup + write kvf ----
        float2 rs[16];
#pragma unroll
        for (int m = 0; m < 4; ++m)
#pragma unroll
            for (int j = 0; j < 4; ++j)
                rs[m * 4 + j] = rowstat[m * 16 + ((lane >> 4) << 2) + j];
#pragma unroll
        for (int m = 0; m < 4; ++m)
#pragma unroll
            for (int n = 0; n < 2; ++n)
#pragma unroll
                for (int j = 0; j < 4; ++j) {
                    int row = m * 16 + ((lane >> 4) << 2) + j;
                    int col = w * 32 + n * 16 + (lane & 15);
                    float val = fmaf(rs[m * 4 + j].x, acc[m][n][j],
                                     fmaf(-rs[m * 4 + j].y, c1r[n], c2r[n]));
                    kvf[row * 130 + col] = val;
                }
        __syncthreads();

        // ---- P4: bf16 store of k,v + wave0 softmax weights ----
        {
            int r = t >> 2, q4 = t & 3;
            unsigned short* dst = ((q4 < 2) ? kb : vb) + (row0 + r) * 64 + (q4 & 1) * 32;
            const float* src = &kvf[r * 130 + q4 * 32];
#pragma unroll
            for (int j = 0; j < 32; j += 8) {
                float2 p0 = *(const float2*)(src + j);
                float2 p1 = *(const float2*)(src + j + 2);
                float2 p2 = *(const float2*)(src + j + 4);
                float2 p3 = *(const float2*)(src + j + 6);
                uint4 o;
                o.x = pkbf(p0.x, p0.y);
                o.y = pkbf(p1.x, p1.y);
                o.z = pkbf(p2.x, p2.y);
                o.w = pkbf(p3.x, p3.y);
                *(uint4*)(dst + j) = o;
            }
        }
        if (t < 64) {
            int r = t;
            float l0 = 0.f, l1 = 0.f, l2 = 0.f;
#pragma unroll 8
            for (int c = 0; c < 64; c += 2) {
                float2 kv2 = *(const float2*)&kvf[r * 130 + c];
                l0 += kv2.x * q_s[c] + kv2.y * q_s[c + 1];
                l1 += kv2.x * q_s[64 + c] + kv2.y * q_s[64 + c + 1];
                l2 += kv2.x * q_s[128 + c] + kv2.y * q_s[128 + c + 1];
            }
            float mx = fmaxf(l0, fmaxf(l1, l2));
            float e0 = expf(l0 - mx), e1 = expf(l1 - mx), e2 = expf(l2 - mx);
            float inv = 1.f / (e0 + e1 + e2);
            w_s[r * 4 + 0] = e0 * inv + 1e-8f;
            w_s[r * 4 + 1] = e1 * inv + 1e-8f;
            w_s[r * 4 + 2] = e2 * inv + 1e-8f;
        }
        __syncthreads();

        // ---- P5: outer-product partial accumulate ----
        if (t < 192) {
            int s = t >> 6, c = t & 63;
            float a = 0.f;
            for (int r = 0; r < 64; ++r) a += w_s[r * 4 + s] * kvf[r * 130 + 64 + c];
            upd_acc += a;
        } else if (t < 195) {
            int s = t - 192;
            float a = 0.f;
            for (int r = 0; r < 64; ++r) a += w_s[r * 4 + s];
            sw_acc += a;
        }
    }
    if (t < 192) partials[(size_t)t * PSTRIDE + blockIdx.x] = upd_acc;
    else if (t < 195) partials[(size_t)t * PSTRIDE + blockIdx.x] = sw_acc;
}

// ------- iter 2: attention with q2, writes attn.T + partials (transposed) -------
__global__ __launch_bounds__(256) void iter2_kernel(
    const unsigned short* __restrict__ kb, const unsigned short* __restrict__ vb,
    const float* __restrict__ qv, float* __restrict__ attn_out, float* __restrict__ partials) {
    __shared__ float q_s[192];
    __shared__ float w_s[256 * 4];
    __shared__ unsigned short v_lds[256 * 64];
    int t = threadIdx.x;
    if (t < 192) q_s[t] = qv[t];
    __syncthreads();
    size_t r = (size_t)blockIdx.x * 256 + t;
    const unsigned short* krow = kb + r * 64;
    float l0 = 0.f, l1 = 0.f, l2 = 0.f;
#pragma unroll
    for (int i = 0; i < 8; ++i) {
        uint4 u = *(const uint4*)(krow + i * 8);
        unsigned uu[4] = {u.x, u.y, u.z, u.w};
#pragma unroll
        for (int p = 0; p < 4; ++p) {
            float fa = bf2f((unsigned short)(uu[p] & 0xffffu));
            float fb = bf2f((unsigned short)(uu[p] >> 16));
            int c = i * 8 + p * 2;
            l0 += fa * q_s[c] + fb * q_s[c + 1];
            l1 += fa * q_s[64 + c] + fb * q_s[64 + c + 1];
            l2 += fa * q_s[128 + c] + fb * q_s[128 + c + 1];
        }
    }
    float mx = fmaxf(l0, fmaxf(l1, l2));
    float e0 = expf(l0 - mx), e1 = expf(l1 - mx), e2 = expf(l2 - mx);
    float inv = 1.f / (e0 + e1 + e2);
    float a0 = e0 * inv, a1 = e1 * inv, a2 = e2 * inv;
    attn_out[r] = a0;
    attn_out[(size_t)N_TOK + r] = a1;
    attn_out[2 * (size_t)N_TOK + r] = a2;
    w_s[t * 4 + 0] = a0 + 1e-8f;
    w_s[t * 4 + 1] = a1 + 1e-8f;
    w_s[t * 4 + 2] = a2 + 1e-8f;
    {
        const uint4* vr = (const uint4*)(vb + r * 64);
        uint4* vl = (uint4*)(v_lds + t * 64);
#pragma unroll
        for (int i = 0; i < 8; ++i) vl[i] = vr[i];
    }
    __syncthreads();
    if (t < 192) {
        int s = t >> 6, c = t & 63;
        float part = 0.f;
        for (int r2 = 0; r2 < 256; ++r2) part += w_s[r2 * 4 + s] * bf2f(v_lds[r2 * 64 + c]);
        partials[(size_t)t * PSTRIDE + blockIdx.x] = part;
    } else if (t < 195) {
        int s = t - 192;
        float part = 0.f;
        for (int r2 = 0; r2 < 256; ++r2) part += w_s[r2 * 4 + s];
        partials[(size_t)t * PSTRIDE + blockIdx.x] = part;
    }
}

// ------- reduce: 195 blocks, one per column -------
__global__ __launch_bounds__(256) void reduce_kernel(const float* __restrict__ partials,
                                                     int nblk, float* __restrict__ reduced) {
    int col = blockIdx.x, t = threadIdx.x;
    float a = 0.f;
    for (int b = t; b < nblk; b += 256) a += partials[(size_t)col * PSTRIDE + b];
#pragma unroll
    for (int d = 1; d < 64; d <<= 1) a += __shfl_xor(a, d);
    __shared__ float ws_[4];
    if ((t & 63) == 0) ws_[t >> 6] = a;
    __syncthreads();
    if (t == 0) reduced[col] = (ws_[0] + ws_[1]) + (ws_[2] + ws_[3]);
}

// ------- update: GRU -> MLP -> (q | out slots) -------
__global__ __launch_bounds__(256) void update_kernel(
    const float* __restrict__ reduced,
    float* __restrict__ slots_ws, float* __restrict__ q_ws,
    const float* __restrict__ gbg_k, const float* __restrict__ gbg_rk, const float* __restrict__ gbg_bias,
    const float* __restrict__ gfg_k, const float* __restrict__ gfg_rk, const float* __restrict__ gfg_bias,
    const float* __restrict__ mbg_g, const float* __restrict__ mbg_b, const float* __restrict__ mbg_W1,
    const float* __restrict__ mbg_b1, const float* __restrict__ mbg_W2, const float* __restrict__ mbg_b2,
    const float* __restrict__ mfg_g, const float* __restrict__ mfg_b, const float* __restrict__ mfg_W1,
    const float* __restrict__ mfg_b1, const float* __restrict__ mfg_W2, const float* __restrict__ mfg_b2,
    const float* __restrict__ qbg_g, const float* __restrict__ qbg_b, const float* __restrict__ qbg_W,
    const float* __restrict__ qfg_g, const float* __restrict__ qfg_b, const float* __restrict__ qfg_W,
    int compute_q, float* __restrict__ out_slots) {
    __shared__ float upd[192], hslots[192], swv[3];
    __shared__ float xm[192], hm[192], gout[64], lnv[64], hid[64];
    int t = threadIdx.x;
    if (t < 192) { hslots[t] = slots_ws[t]; upd[t] = reduced[t]; }
    else if (t < 195) swv[t - 192] = reduced[t];
    __syncthreads();
    if (t < 192) upd[t] = upd[t] / swv[t >> 6];
    __syncthreads();

    for (int s = 0; s < 3; ++s) {
        const float* K = s ? gfg_k : gbg_k;
        const float* RK = s ? gfg_rk : gbg_rk;
        const float* BS = s ? gfg_bias : gbg_bias;
        if (t < 192) {
            float ax = BS[t], ah = BS[192 + t];
            const float* us = upd + s * 64;
            const float* hs = hslots + s * 64;
            for (int i = 0; i < 64; ++i) {
                ax += us[i] * K[i * 192 + t];
                ah += hs[i] * RK[i * 192 + t];
            }
            xm[t] = ax; hm[t] = ah;
        }
        __syncthreads();
        if (t < 64) {
            float z = sigmoidf_(xm[t] + hm[t]);
            float rg = sigmoidf_(xm[64 + t] + hm[64 + t]);
            float cand = tanhf(xm[128 + t] + rg * hm[128 + t]);
            gout[t] = z * hslots[s * 64 + t] + (1.f - z) * cand;
        }
        __syncthreads();
        const float* MG = s ? mfg_g : mbg_g;
        const float* MB = s ? mfg_b : mbg_b;
        const float* MW1 = s ? mfg_W1 : mbg_W1;
        const float* MB1 = s ? mfg_b1 : mbg_b1;
        const float* MW2 = s ? mfg_W2 : mbg_W2;
        const float* MB2 = s ? mfg_b2 : mbg_b2;
        if (t < 64) {
            float v = gout[t];
            float su = v, sq = v * v;
#pragma unroll
            for (int d = 1; d < 64; d <<= 1) { su += __shfl_xor(su, d); sq += __shfl_xor(sq, d); }
            float mean = su * (1.f / 64.f), var = sq * (1.f / 64.f) - mean * mean;
            float rstd = rsqrtf(var + 1e-3f);
            lnv[t] = (v - mean) * rstd * MG[t] + MB[t];
        }
        __syncthreads();
        if (t < 64) {
            float a = MB1[t];
            for (int i = 0; i < 64; ++i) a += lnv[i] * MW1[i * 64 + t];
            hid[t] = fmaxf(a, 0.f);
        }
        __syncthreads();
        if (t < 64) {
            float a = MB2[t];
            for (int i = 0; i < 64; ++i) a += hid[i] * MW2[i * 64 + t];
            hslots[s * 64 + t] = gout[t] + a;
        }
        __syncthreads();
    }
    if (t < 192) {
        slots_ws[t] = hslots[t];
        if (out_slots) out_slots[t] = hslots[t];
        if (compute_q) {
            int s = t >> 6, lane = t & 63;
            const float* g = s ? qfg_g : qbg_g;
            const float* b = s ? qfg_b : qbg_b;
            const float* W = s ? qfg_W : qbg_W;
            q_ws[t] = q_from_slot(hslots[t], g, b, W, lane);
        }
    }
}

extern "C" void kernel_launch(void* const* d_in, const int* in_sizes, int n_in,
                              void* d_out, int out_size, void* d_ws, size_t ws_size,
                              hipStream_t stream) {
    const float* x        = (const float*)d_in[0];
    const float* noise_fg = (const float*)d_in[1];
    const float* noise_bg = (const float*)d_in[2];
    const float* ln_g     = (const float*)d_in[3];
    const float* ln_b     = (const float*)d_in[4];
    const float* mu_fg    = (const float*)d_in[5];
    const float* ls_fg    = (const float*)d_in[6];
    const float* mu_bg    = (const float*)d_in[7];
    const float* ls_bg    = (const float*)d_in[8];
    const float* Wk       = (const float*)d_in[9];
    const float* Wv       = (const float*)d_in[10];
    const float* qfg_g    = (const float*)d_in[11];
    const float* qfg_b    = (const float*)d_in[12];
    const float* qfg_W    = (const float*)d_in[13];
    const float* qbg_g    = (const float*)d_in[14];
    const float* qbg_b    = (const float*)d_in[15];
    const float* qbg_W    = (const float*)d_in[16];
    const float* gfg_k    = (const float*)d_in[17];
    const float* gfg_rk   = (const float*)d_in[18];
    const float* gfg_bias = (const float*)d_in[19];
    const float* gbg_k    = (const float*)d_in[20];
    const float* gbg_rk   = (const float*)d_in[21];
    const float* gbg_bias = (const float*)d_in[22];
    const float* mfg_g    = (const float*)d_in[23];
    const float* mfg_b    = (const float*)d_in[24];
    const float* mfg_W1   = (const float*)d_in[25];
    const float* mfg_b1   = (const float*)d_in[26];
    const float* mfg_W2   = (const float*)d_in[27];
    const float* mfg_b2   = (const float*)d_in[28];
    const float* mbg_g    = (const float*)d_in[29];
    const float* mbg_b    = (const float*)d_in[30];
    const float* mbg_W1   = (const float*)d_in[31];
    const float* mbg_b1   = (const float*)d_in[32];
    const float* mbg_W2   = (const float*)d_in[33];
    const float* mbg_b2   = (const float*)d_in[34];

    char* ws = (char*)d_ws;
    unsigned short* Wt = (unsigned short*)ws;                  // 131072 B
    float* c12 = (float*)(ws + 131072);                        // 1024 B
    unsigned short* kb = (unsigned short*)(ws + 132096);       // 32 MB
    unsigned short* vb = kb + (size_t)N_TOK * 64;              // 32 MB
    char* ws2 = ws + 132096 + (size_t)2 * N_TOK * 64 * 2;
    float* slots_ws = (float*)ws2;                             // 192
    float* q_ws = slots_ws + 192;                              // 192
    float* reduced = q_ws + 192;                               // 256 (padded)
    float* partials = reduced + 256;                           // 195 * PSTRIDE

    float* out = (float*)d_out;

    wt_init_kernel<<<dim3(129), dim3(256), 0, stream>>>(
        Wk, Wv, ln_g, ln_b, Wt, c12,
        noise_fg, noise_bg, mu_fg, ls_fg, mu_bg, ls_bg,
        qbg_g, qbg_b, qbg_W, qfg_g, qfg_b, qfg_W, slots_ws, q_ws);
    phaseA_kernel<<<dim3(NBLK_A), dim3(256), 0, stream>>>(x, Wt, c12, q_ws, kb, vb, partials);
    reduce_kernel<<<dim3(195), dim3(256), 0, stream>>>(partials, NBLK_A, reduced);
    update_kernel<<<dim3(1), dim3(256), 0, stream>>>(reduced, slots_ws, q_ws,
        gbg_k, gbg_rk, gbg_bias, gfg_k, gfg_rk, gfg_bias,
        mbg_g, mbg_b, mbg_W1, mbg_b1, mbg_W2, mbg_b2,
        mfg_g, mfg_b, mfg_W1, mfg_b1, mfg_W2, mfg_b2,
        qbg_g, qbg_b, qbg_W, qfg_g, qfg_b, qfg_W, 1, (float*)nullptr);
    iter2_kernel<<<dim3(NBLK_I2), dim3(256), 0, stream>>>(kb, vb, q_ws, out + 192, partials);
    reduce_kernel<<<dim3(195), dim3(256), 0, stream>>>(partials, NBLK_I2, reduced);
    update_kernel<<<dim3(1), dim3(256), 0, stream>>>(reduced, slots_ws, q_ws,
        gbg_k, gbg_rk, gbg_bias, gfg_k, gfg_rk, gfg_bias,
        mbg_g, mbg_b, mbg_W1, mbg_b1, mbg_W2, mbg_b2,
        mfg_g, mfg_b, mfg_W1, mfg_b1, mfg_W2, mfg_b2,
        qbg_g, qbg_b, qbg_W, qfg_g, qfg_b, qfg_W, 0, out);
}